// Round 12
// baseline (660.985 us; speedup 1.0000x reference)
//
#include <hip/hip_runtime.h>
#include <cstdint>
#include <cstddef>

#define N_NODESC 100000
#define N_EDGESC 400000
#define N_GRAPHSC 2048
#define F_INC 78
#define HEADS1C 10
#define D1C 78           // per-head out dim, layer 1
#define F1C 780          // HEADS1C * D1C
#define OUT2C 128
#define E_TOTC (N_EDGESC + N_NODESC)   // 500000 edges incl. self-loops

typedef unsigned short ushort_t;
typedef __attribute__((ext_vector_type(8))) short short8;
typedef __attribute__((ext_vector_type(4))) float f32x4;
typedef __attribute__((ext_vector_type(4))) unsigned int uint4v;
union U4S8 { uint4v u; short8 s; };

static __device__ __forceinline__ float lrelu(float x){ return x > 0.f ? x : 0.2f*x; }

// fast ELU: v_exp_f32-based (expm1f was ~25 VALU inst; __expf is 2).
static __device__ __forceinline__ float elu_fast(float v){
  return (v > 0.f) ? v : (__expf(v) - 1.0f);
}

// LDS-only barrier: __syncthreads on gfx950 drains vmcnt(0) too, which kills
// in-flight global prefetches.  This waits LDS ops only and leaves global
// loads in flight across the barrier.
static __device__ __forceinline__ void bar_lds(){
  asm volatile("s_waitcnt lgkmcnt(0)" ::: "memory");
  __builtin_amdgcn_s_barrier();
}

// bf16 helpers (round-to-nearest-even)
static __device__ __forceinline__ unsigned short f2bf(float f){
  unsigned int u = __float_as_uint(f);
  unsigned int r = (u + 0x7fffu + ((u >> 16) & 1u)) >> 16;
  return (unsigned short)r;
}
static __device__ __forceinline__ float bf2f(unsigned short h){
  return __uint_as_float(((unsigned int)h) << 16);
}

// ---------------- CSR build ----------------
__global__ void k_deg(const int* __restrict__ ei, int* __restrict__ deg){
  int e = blockIdx.x*256 + threadIdx.x;
  if (e >= E_TOTC) return;
  int dst = (e < N_EDGESC) ? ei[N_EDGESC + e] : (e - N_EDGESC);
  atomicAdd(&deg[dst], 1);
}

__global__ __launch_bounds__(1024) void k_scan1(const int* __restrict__ deg,
                                                int* __restrict__ rowptr,
                                                int* __restrict__ bsum){
  __shared__ int s[1024];
  int t = threadIdx.x, i = blockIdx.x*1024 + t;
  int v = (i < N_NODESC) ? deg[i] : 0;
  s[t] = v; __syncthreads();
  for (int d = 1; d < 1024; d <<= 1){
    int xv = (t >= d) ? s[t-d] : 0;
    __syncthreads();
    s[t] += xv;
    __syncthreads();
  }
  if (i < N_NODESC) rowptr[i+1] = s[t];
  if (t == 1023) bsum[blockIdx.x] = s[t];
}

__global__ void k_scan2(int* __restrict__ bsum, int* __restrict__ rowptr, int nb){
  if (threadIdx.x == 0 && blockIdx.x == 0){
    int run = 0;
    for (int b = 0; b < nb; b++){ int v = bsum[b]; bsum[b] = run; run += v; }
    rowptr[0] = 0;
  }
}

__global__ __launch_bounds__(1024) void k_scan3(int* __restrict__ rowptr,
                                                const int* __restrict__ bsum){
  int i = blockIdx.x*1024 + threadIdx.x;
  if (i < N_NODESC) rowptr[i+1] += bsum[blockIdx.x];
}

__global__ void k_scatter(const int* __restrict__ ei, const int* __restrict__ rowptr,
                          int* __restrict__ cnt, int* __restrict__ esrc){
  int e = blockIdx.x*256 + threadIdx.x;
  if (e >= E_TOTC) return;
  int src, dst;
  if (e < N_EDGESC){ src = ei[e]; dst = ei[N_EDGESC + e]; }
  else { src = dst = e - N_EDGESC; }
  int pos = rowptr[dst] + atomicAdd(&cnt[dst], 1);
  esrc[pos] = src;
}

// ---------------- layer-1 attention logit precompute ----------------
__global__ void k_wa1(const float* __restrict__ W1, const float* __restrict__ a_src1,
                      const float* __restrict__ a_dst1, float* __restrict__ Wa1){
  int i = blockIdx.x*256 + threadIdx.x;
  if (i >= F_INC*2*HEADS1C) return;
  int d = i / (2*HEADS1C), c = i % (2*HEADS1C);
  const float* a = (c < HEADS1C) ? a_src1 : a_dst1;
  int h = (c < HEADS1C) ? c : c - HEADS1C;
  float s = 0.f;
  for (int j = 0; j < D1C; j++) s += W1[d*F1C + h*D1C + j] * a[h*D1C + j];
  Wa1[d*(2*HEADS1C) + c] = s;
}

// one thread per node; acc[20] in regs; x read once via float2.
__global__ __launch_bounds__(256) void k_att1(const float* __restrict__ x,
                                              const float* __restrict__ Wa1,
                                              float* __restrict__ att1){
  int n = blockIdx.x*256 + threadIdx.x;
  if (n >= N_NODESC) return;
  const float* xr = x + (size_t)n*F_INC;
  float acc[20];
  #pragma unroll
  for (int c = 0; c < 20; c++) acc[c] = 0.f;
  for (int d0 = 0; d0 < F_INC; d0 += 2){
    float2 xv = *(const float2*)(xr + d0);
    const float* w0 = Wa1 + d0*20;
    #pragma unroll
    for (int c = 0; c < 20; c++)
      acc[c] += xv.x*w0[c] + xv.y*w0[20 + c];
  }
  float* o = att1 + (size_t)n*20;
  #pragma unroll
  for (int j = 0; j < 10; j++){
    float2 ov; ov.x = acc[2*j]; ov.y = acc[2*j+1];
    *(float2*)(o + 2*j) = ov;
  }
}

// one thread per node, all 10 heads at once; float2-vectorized gathers.
__global__ __launch_bounds__(256) void k_stats1(const float* __restrict__ att1,
                                                const int* __restrict__ rowptr,
                                                const int* __restrict__ esrc,
                                                float* __restrict__ stat1){
  int n = blockIdx.x*256 + threadIdx.x;
  if (n >= N_NODESC) return;
  float ad[10];
  {
    const float* a = att1 + (size_t)n*20 + 10;
    #pragma unroll
    for (int j = 0; j < 5; j++){
      float2 v = *(const float2*)(a + 2*j);
      ad[2*j] = v.x; ad[2*j+1] = v.y;
    }
  }
  int b = rowptr[n], e = rowptr[n+1];
  float m[10];
  #pragma unroll
  for (int h = 0; h < 10; h++) m[h] = -1e30f;
  for (int p = b; p < e; p += 2){
    int s0 = esrc[p];
    int s1 = esrc[(p+1 < e) ? p+1 : p];
    float2 v0[5], v1[5];
    #pragma unroll
    for (int j = 0; j < 5; j++) v0[j] = *(const float2*)(att1 + (size_t)s0*20 + 2*j);
    #pragma unroll
    for (int j = 0; j < 5; j++) v1[j] = *(const float2*)(att1 + (size_t)s1*20 + 2*j);
    #pragma unroll
    for (int h = 0; h < 10; h++){
      float a0 = (h & 1) ? v0[h>>1].y : v0[h>>1].x;
      m[h] = fmaxf(m[h], lrelu(a0 + ad[h]));
    }
    if (p+1 < e){
      #pragma unroll
      for (int h = 0; h < 10; h++){
        float a1 = (h & 1) ? v1[h>>1].y : v1[h>>1].x;
        m[h] = fmaxf(m[h], lrelu(a1 + ad[h]));
      }
    }
  }
  float den[10];
  #pragma unroll
  for (int h = 0; h < 10; h++) den[h] = 0.f;
  for (int p = b; p < e; p += 2){
    int s0 = esrc[p];
    int s1 = esrc[(p+1 < e) ? p+1 : p];
    float2 v0[5], v1[5];
    #pragma unroll
    for (int j = 0; j < 5; j++) v0[j] = *(const float2*)(att1 + (size_t)s0*20 + 2*j);
    #pragma unroll
    for (int j = 0; j < 5; j++) v1[j] = *(const float2*)(att1 + (size_t)s1*20 + 2*j);
    #pragma unroll
    for (int h = 0; h < 10; h++){
      float a0 = (h & 1) ? v0[h>>1].y : v0[h>>1].x;
      den[h] += expf(lrelu(a0 + ad[h]) - m[h]);
    }
    if (p+1 < e){
      #pragma unroll
      for (int h = 0; h < 10; h++){
        float a1 = (h & 1) ? v1[h>>1].y : v1[h>>1].x;
        den[h] += expf(lrelu(a1 + ad[h]) - m[h]);
      }
    }
  }
  float* o = stat1 + (size_t)n*20;
  #pragma unroll
  for (int h = 0; h < 10; h++){
    o[h] = m[h];
    o[10 + h] = 1.f/(den[h] + 1e-16f);
  }
}

// LDS-free aggregation (v9): lane = feature d; coalesced x gathers, alpha
// broadcast via shfl; 4 independent waves per block, zero LDS/barriers.
__global__ __launch_bounds__(256) void k_agg1(
    const float* __restrict__ x, const float* __restrict__ att1,
    const float* __restrict__ stat1, const int* __restrict__ rowptr,
    const int* __restrict__ esrc, ushort_t* __restrict__ zc, int base){
  int wv = threadIdx.x >> 6;
  int l  = threadIdx.x & 63;
  int nl = blockIdx.x*4 + wv;          // chunk-local node index (grid = R/4)
  int n  = base + nl;
  int b = rowptr[n], e = rowptr[n+1];
  float ad = 0.f, mm = 0.f, rd = 0.f;
  if (l < HEADS1C){
    ad = att1[n*20 + 10 + l];
    mm = stat1[n*20 + l];
    rd = stat1[n*20 + 10 + l];
  }
  float acc0[10], acc1[10];
  #pragma unroll
  for (int h = 0; h < 10; h++){ acc0[h] = 0.f; acc1[h] = 0.f; }
  bool lo14 = (l < 14);
  for (int p = b; p < e; p += 4){
    int c = e - p; if (c > 4) c = 4;
    int ss[4];
    #pragma unroll
    for (int j = 0; j < 4; j++) ss[j] = esrc[p + (j < c ? j : 0)];
    float alv[4];
    #pragma unroll
    for (int j = 0; j < 4; j++){
      float av = (l < HEADS1C) ? att1[ss[j]*20 + l] : 0.f;
      float ev = lrelu(av + ad);
      alv[j] = (j < c) ? expf(ev - mm) * rd : 0.f;
    }
    float xv0[4], xv1[4];
    #pragma unroll
    for (int j = 0; j < 4; j++){
      const float* xr = x + (size_t)ss[j]*F_INC;
      xv0[j] = xr[l];
      xv1[j] = lo14 ? xr[64 + l] : 0.f;
    }
    #pragma unroll
    for (int h = 0; h < 10; h++){
      float a0 = __shfl(alv[0], h);
      float a1 = __shfl(alv[1], h);
      float a2 = __shfl(alv[2], h);
      float a3 = __shfl(alv[3], h);
      float s0 = a0*xv0[0] + a1*xv0[1] + a2*xv0[2] + a3*xv0[3];
      float s1 = a0*xv1[0] + a1*xv1[1] + a2*xv1[2] + a3*xv1[3];
      acc0[h] += s0;
      acc1[h] += s1;
    }
  }
  ushort_t* zr = zc + (size_t)nl*F1C;
  #pragma unroll
  for (int h = 0; h < 10; h++){
    zr[h*78 + l] = f2bf(acc0[h]);
    if (lo14) zr[h*78 + 64 + l] = f2bf(acc1[h]);
  }
}

// ---------------- weight pre-transpose (zero-padded bf16) ----------------
__global__ void k_prepW1(const float* __restrict__ W1, ushort_t* __restrict__ W1t){
  // W1t[h][n(80)][k(96)] = bf16(W1[k][h*78+n]) with zero pad
  int i = blockIdx.x*256 + threadIdx.x;
  if (i >= HEADS1C*80*96) return;
  int h = i / (80*96), rem = i % (80*96), n = rem / 96, k = rem % 96;
  float v = (n < D1C && k < F_INC) ? W1[(size_t)k*F1C + h*D1C + n] : 0.f;
  W1t[i] = f2bf(v);
}

// W2f[h][n(128)][k(96)] = bf16(W2[h*78+k][n]) with zero pad in k (78..95)
__global__ void k_prepW2f(const float* __restrict__ W2, ushort_t* __restrict__ W2f){
  int i = blockIdx.x*256 + threadIdx.x;
  if (i >= HEADS1C*128*96) return;
  int h = i / (128*96), rem = i % (128*96), n = rem / 96, k = rem % 96;
  float v = (k < D1C) ? W2[(size_t)(h*D1C + k)*OUT2C + n] : 0.f;
  W2f[i] = f2bf(v);
}

// generic: Wt[n][k(KB)] = bf16(W[k][n]) zero-padded in k
__global__ void k_prepWt(const float* __restrict__ W, ushort_t* __restrict__ Wt,
                         int Kdim, int Ndim, int KB){
  int i = blockIdx.x*256 + threadIdx.x;
  if (i >= Ndim*KB) return;
  int n = i / KB, k = i % KB;
  float v = (k < Kdim) ? W[(size_t)k*Ndim + n] : 0.f;
  Wt[i] = f2bf(v);
}

__global__ void k_cast_bf(const float* __restrict__ in, ushort_t* __restrict__ o, int n){
  int i = blockIdx.x*256 + threadIdx.x;
  if (i < n) o[i] = f2bf(in[i]);
}

// ---------------- MFMA bf16 GEMM: C[M,N] = act(A @ Bt^T + bias), bf16 out ---
template<int BN, int NT, int KB, int KVAL, int ACT, bool HASBIAS>
__global__ __launch_bounds__(256) void mfma_gemm(
    const ushort_t* __restrict__ A, const ushort_t* __restrict__ Bt,
    const float* __restrict__ bias, ushort_t* __restrict__ C,
    int M, int N, int lda, int ldc,
    int zsA, int zsBt, int zsC, int zsBias)
{
  __shared__ unsigned int As[64][20];   // 64 rows x 32 bf16 (+pad)
  __shared__ unsigned int Bs[BN][20];
  int z = blockIdx.z;
  A += (size_t)z*zsA; Bt += (size_t)z*zsBt; C += (size_t)z*zsC;
  const float* bz = HASBIAS ? (bias + (size_t)z*zsBias) : nullptr;
  int m0 = blockIdx.x*64;
  int n0 = blockIdx.y*BN;
  int t = threadIdx.x;
  int w = t >> 6, lane = t & 63;
  int q = lane >> 4, li = lane & 15;
  f32x4 acc[NT];
  #pragma unroll
  for (int i = 0; i < NT; i++) acc[i] = (f32x4){0.f,0.f,0.f,0.f};

  int am = t >> 2;           // staged row 0..63
  int ak0 = (t & 3)*8;       // short col base 0,8,16,24
  int gm = m0 + am;
  bool rv = (gm < M);

  #pragma unroll
  for (int ki = 0; ki < KB/32; ki++){
    const int kt = ki*32;
    int nv;
    if (ki == KB/32 - 1){
      int d = KVAL - ak0; nv = d < 0 ? 0 : (d > 8 ? 8 : d);
    } else nv = 8;
    {
      unsigned u0=0u, u1=0u, u2=0u, u3=0u;
      if (rv && nv > 0){
        const unsigned int* ap = (const unsigned int*)(A + (size_t)gm*lda + kt + ak0);
        u0 = ap[0]; u1 = ap[1]; u2 = ap[2]; u3 = ap[3];
        int ndw = nv >> 1;
        if (ndw < 4) u3 = 0u;
        if (ndw < 3) u2 = 0u;
        if (ndw < 2) u1 = 0u;
      }
      int c0 = (t & 3)*4;
      As[am][c0] = u0; As[am][c0+1] = u1; As[am][c0+2] = u2; As[am][c0+3] = u3;
    }
    for (int g = t; g < BN*4; g += 256){
      int n = g >> 2, c0 = (g & 3)*4;
      const unsigned int* bp = (const unsigned int*)(Bt + (size_t)(n0 + n)*KB + kt + c0*2);
      Bs[n][c0] = bp[0]; Bs[n][c0+1] = bp[1]; Bs[n][c0+2] = bp[2]; Bs[n][c0+3] = bp[3];
    }
    __syncthreads();
    U4S8 a; a.u = *(const uint4v*)&As[w*16 + li][q*4];
    #pragma unroll
    for (int nt = 0; nt < NT; nt++){
      U4S8 b; b.u = *(const uint4v*)&Bs[nt*16 + li][q*4];
      acc[nt] = __builtin_amdgcn_mfma_f32_16x16x32_bf16(a.s, b.s, acc[nt], 0, 0, 0);
    }
    __syncthreads();
  }
  #pragma unroll
  for (int nt = 0; nt < NT; nt++){
    int col = n0 + nt*16 + li;
    if (col >= N) continue;
    float bv = HASBIAS ? bz[col] : 0.f;
    #pragma unroll
    for (int r = 0; r < 4; r++){
      int gmr = m0 + w*16 + q*4 + r;
      if (gmr >= M) continue;
      float v = acc[nt][r] + bv;
      if (ACT == 1) v = fmaxf(v, 0.f);
      else if (ACT == 2) v = (v > 0.f) ? v : (__expf(v) - 1.0f);
      C[(size_t)gmr*ldc + col] = f2bf(v);
    }
  }
}

// ---------------- FUSED layer-1 GEMM + projection (v12) ----------------
// h2pre[m, 0:128] = sum_h  elu( zc[m, h*78:+78] @ W1h + b1_h )  @  W2[h*78:+78, 0:128]
// + fused att2 logits from the bf16-rounded h2pre values.
//
// v12 = v11 with ONE change: Bs1/Bs2 row stride 48 -> 49 dwords.  Stride 48
// is 16 mod 32: the MFMA B-fragment reads Bs[(nt*16+li)*48 + ...] fold 16
// lanes onto 2 bank pairs (8-way conflict) on EVERY ds_read_b128 — these are
// 13 of 15 b128 reads per ki iteration and ~16% of kernel cycles
// (SQ_LDS_BANK_CONFLICT 1.05e7).  Stride 49 (odd) -> li*49 mod 32 hits 16
// distinct banks -> conflict-free.  LDS 54080B (<= 160KB/3): 3 blocks/CU kept.
#define BS_STRIDE 49
__global__ __launch_bounds__(256, 3) void mfma_fused12(
    const ushort_t* __restrict__ zc, const ushort_t* __restrict__ W1t,
    const float* __restrict__ b1, const ushort_t* __restrict__ W2f,
    ushort_t* __restrict__ h2pre, float* __restrict__ att2,
    const float* __restrict__ a_src2, const float* __restrict__ a_dst2,
    int M)
{
  __shared__ unsigned int Bs1[80*BS_STRIDE];   // W1t[h]: 80 rows x 48 dw + 1 pad
  __shared__ unsigned int Bs2[128*BS_STRIDE];  // W2f[h]: 128 rows x 48 dw + 1 pad
  __shared__ unsigned int Ts[64][52];   // T bf16 (96 shorts + pad), wave-private rows
  int m0 = blockIdx.x*64;
  int t = threadIdx.x;
  int w = t >> 6, lane = t & 63;
  int q = lane >> 4, li = lane & 15;

  const uint4v* w1v = (const uint4v*)W1t;   // [h*960 + g] 16B groups
  const uint4v* w2v = (const uint4v*)W2f;   // [h*1536 + g]

  // ---- staging-register helpers (T14 split: issue early, ds_write late) ----
  uint4v rw1[4], rw2[6];
  auto issueW1 = [&](int h){
    #pragma unroll
    for (int g0 = 0; g0 < 4; g0++){
      int g = t + g0*256;
      if (g < 960) rw1[g0] = w1v[(size_t)h*960 + g];
    }
  };
  auto writeW1 = [&](){
    #pragma unroll
    for (int g0 = 0; g0 < 4; g0++){
      int g = t + g0*256;
      if (g < 960){
        int n = g/12, c0 = (g%12)*4;
        *(uint4v*)&Bs1[n*BS_STRIDE + c0] = rw1[g0];
      }
    }
  };
  auto issueW2 = [&](int h){
    #pragma unroll
    for (int g0 = 0; g0 < 6; g0++)
      rw2[g0] = w2v[(size_t)h*1536 + t + g0*256];
  };
  auto writeW2 = [&](){
    #pragma unroll
    for (int g0 = 0; g0 < 6; g0++){
      int g = t + g0*256;
      int n = g/12, c0 = (g%12)*4;
      *(uint4v*)&Bs2[n*BS_STRIDE + c0] = rw2[g0];
    }
  };

  f32x4 acc2[8];
  #pragma unroll
  for (int i = 0; i < 8; i++) acc2[i] = (f32x4){0.f,0.f,0.f,0.f};

  issueW1(0);                           // both head-0 weight tiles in flight
  issueW2(0);

  // zero Ts pad dwords 39..47 (cols 78..95) once (read in stage-2 ki=2;
  // published by the prologue barrier)
  for (int i = t; i < 64*9; i += 256) Ts[i/9][39 + i%9] = 0u;

  // this lane's A row: m0 + w*16 + li; k-chunk q (shorts q*8..q*8+7 per 32-k tile)
  int ar = m0 + w*16 + li;
  bool rv = (ar < M);
  const unsigned int* abase = (const unsigned int*)(zc + (size_t)ar*F1C);

  // A-fragment loader for head h: af[ki], k = ki*32 + q*8 (head slice is 78 wide)
  auto lda = [&](int h, uint4v* af){
    af[0] = (uint4v){0u,0u,0u,0u};
    af[1] = (uint4v){0u,0u,0u,0u};
    af[2] = (uint4v){0u,0u,0u,0u};
    if (rv){
      const unsigned int* p = abase + h*39 + q*4;    // h*78 shorts = h*39 dwords
      af[0][0]=p[0];  af[0][1]=p[1];  af[0][2]=p[2];  af[0][3]=p[3];
      af[1][0]=p[16]; af[1][1]=p[17]; af[1][2]=p[18]; af[1][3]=p[19];
      if (q < 2){                                    // k 64..79 only (78,79 zeroed)
        af[2][0]=p[32]; af[2][1]=p[33]; af[2][2]=p[34]; af[2][3]=p[35];
        if (q == 1) af[2][3] = 0u;
      }
    }
  };

  uint4v acur[3], anxt[3];
  lda(0, acur);

  writeW1();                            // Bs1 <- W1[0] (vmcnt wait, once)
  bar_lds();                            // Bs1 + Ts-pad visible

  #pragma unroll 1
  for (int h = 0; h < HEADS1C; h++){
    int hn = (h+1 < HEADS1C) ? h+1 : 0;
    writeW2();                          // Bs2 <- W2[h]; rw2 dies (stage-1 reads Bs1)
    issueW1(hn);                        // W1[h+1] -> regs, in flight over stage-1
    // per-head bias: 5 per lane (cols nt*16+li)
    float bv[5];
    #pragma unroll
    for (int nt = 0; nt < 5; nt++){
      int col = nt*16 + li;
      bv[nt] = (col < D1C) ? b1[h*D1C + col] : 0.f;
    }

    // stage-1 MFMA: T(64x80) = zc_h @ W1h (A from registers, B from Bs1)
    f32x4 acc1[5];
    #pragma unroll
    for (int i = 0; i < 5; i++) acc1[i] = (f32x4){0.f,0.f,0.f,0.f};
    #pragma unroll
    for (int ki = 0; ki < 3; ki++){
      U4S8 a; a.u = acur[ki];
      #pragma unroll
      for (int nt = 0; nt < 5; nt++){
        U4S8 b; b.u = *(const uint4v*)&Bs1[(nt*16 + li)*BS_STRIDE + ki*16 + q*4];
        acc1[nt] = __builtin_amdgcn_mfma_f32_16x16x32_bf16(a.s, b.s, acc1[nt], 0, 0, 0);
      }
    }
    // bias + fast elu -> bf16 into Ts (wave-private rows)
    #pragma unroll
    for (int nt = 0; nt < 5; nt++){
      int col = nt*16 + li;
      #pragma unroll
      for (int r = 0; r < 4; r++){
        int row = w*16 + q*4 + r;
        float v = elu_fast(acc1[nt][r] + bv[nt]);
        ((ushort_t*)&Ts[row][0])[col] = f2bf(v);
      }
    }
    // prefetch next head's A frags (zc, L3) — stays in flight across barriers
    lda(hn, anxt);

    bar_lds();                          // stage-1 Bs1 reads done; Bs2+Ts visible
    writeW1();                          // Bs1 <- W1[h+1]; rw1 dies (stage-2 reads Bs2)
    issueW2(hn);                        // W2[h+1] -> regs, in flight over stage-2

    // stage-2 MFMA: acc2 += T @ W2f[h] (A from own Ts rows, B from Bs2)
    #pragma unroll
    for (int ki = 0; ki < 3; ki++){
      U4S8 a; a.u = *(const uint4v*)&Ts[w*16 + li][ki*16 + q*4];
      #pragma unroll
      for (int nt = 0; nt < 8; nt++){
        U4S8 b; b.u = *(const uint4v*)&Bs2[(nt*16 + li)*BS_STRIDE + ki*16 + q*4];
        acc2[nt] = __builtin_amdgcn_mfma_f32_16x16x32_bf16(a.s, b.s, acc2[nt], 0, 0, 0);
      }
    }
    bar_lds();                          // stage-2 Bs2 reads done; Bs1 writes visible
    acur[0] = anxt[0]; acur[1] = anxt[1]; acur[2] = anxt[2];
  }

  // ---- epilogue: h2pre bf16 + fused att2 logits (from bf16-rounded vals) ---
  float as2[8], ad2[8];
  #pragma unroll
  for (int nt = 0; nt < 8; nt++){
    int col = nt*16 + li;
    as2[nt] = a_src2[col];
    ad2[nt] = a_dst2[col];
  }
  #pragma unroll
  for (int r = 0; r < 4; r++){
    int gmr = m0 + w*16 + q*4 + r;
    float p0 = 0.f, p1 = 0.f;
    ushort_t hv[8];
    #pragma unroll
    for (int nt = 0; nt < 8; nt++){
      ushort_t hb = f2bf(acc2[nt][r]);
      float vb = bf2f(hb);
      p0 += vb*as2[nt]; p1 += vb*ad2[nt];
      hv[nt] = hb;
    }
    #pragma unroll
    for (int off = 1; off < 16; off <<= 1){
      p0 += __shfl_xor(p0, off);
      p1 += __shfl_xor(p1, off);
    }
    if (gmr < M){
      #pragma unroll
      for (int nt = 0; nt < 8; nt++)
        h2pre[(size_t)gmr*OUT2C + nt*16 + li] = hv[nt];
      if (li == 0){
        att2[(size_t)gmr*2]     = p0;
        att2[(size_t)gmr*2 + 1] = p1;
      }
    }
  }
}

// per node: max + 1/(sum exp) + per-edge alpha precompute (3rd pass).
__global__ void k_stats2(const float* __restrict__ att2, const int* __restrict__ rowptr,
                         const int* __restrict__ esrc, float* __restrict__ stat2,
                         float* __restrict__ ealpha){
  int n = blockIdx.x*256 + threadIdx.x;
  if (n >= N_NODESC) return;
  float ad = att2[n*2+1];
  int b = rowptr[n], e = rowptr[n+1];
  float m = -1e30f;
  for (int p = b; p < e; p += 4){
    int c = e - p; if (c > 4) c = 4;
    float v[4];
    #pragma unroll
    for (int j = 0; j < 4; j++){ int s = esrc[p + (j < c ? j : 0)]; v[j] = att2[s*2]; }
    #pragma unroll
    for (int j = 0; j < 4; j++) if (j < c) m = fmaxf(m, lrelu(v[j] + ad));
  }
  float den = 0.f;
  for (int p = b; p < e; p += 4){
    int c = e - p; if (c > 4) c = 4;
    float v[4];
    #pragma unroll
    for (int j = 0; j < 4; j++){ int s = esrc[p + (j < c ? j : 0)]; v[j] = att2[s*2]; }
    #pragma unroll
    for (int j = 0; j < 4; j++) if (j < c) den += expf(lrelu(v[j] + ad) - m);
  }
  float rd = 1.f/(den + 1e-16f);
  stat2[n*2] = m;
  stat2[n*2+1] = rd;
  for (int p = b; p < e; p++){
    int s = esrc[p];
    ealpha[p] = expf(lrelu(att2[s*2] + ad) - m) * rd;
  }
}

// wave per node; alpha loaded precomputed (wave-uniform -> scalarizable);
// inner loop is pure gather + FMA.
__global__ void k_agg2(const ushort_t* __restrict__ h2pre,
                       const float* __restrict__ ealpha,
                       const int* __restrict__ rowptr,
                       const int* __restrict__ esrc, const float* __restrict__ b2,
                       const float* __restrict__ w_gate, const float* __restrict__ b_gate,
                       float* __restrict__ h2, float* __restrict__ wnode){
  int n = blockIdx.x*4 + (threadIdx.x >> 6);
  int l = threadIdx.x & 63;
  if (n >= N_NODESC) return;
  int b = rowptr[n], e = rowptr[n+1];
  float a0 = 0.f, a1 = 0.f;
  for (int p = b; p < e; p += 4){
    int c = e - p; if (c > 4) c = 4;
    int ss[4]; float al[4];
    #pragma unroll
    for (int j = 0; j < 4; j++) ss[j] = esrc[p + (j < c ? j : 0)];
    #pragma unroll
    for (int j = 0; j < 4; j++) al[j] = (j < c) ? ealpha[p + j] : 0.f;
    unsigned u[4];
    #pragma unroll
    for (int j = 0; j < 4; j++) u[j] = *(const unsigned*)(h2pre + (size_t)ss[j]*OUT2C + 2*l);
    #pragma unroll
    for (int j = 0; j < 4; j++){
      a0 += al[j] * bf2f((ushort_t)(u[j] & 0xffffu));
      a1 += al[j] * bf2f((ushort_t)(u[j] >> 16));
    }
  }
  float v0 = fmaxf(a0 + b2[2*l],   0.f);
  float v1 = fmaxf(a1 + b2[2*l+1], 0.f);
  float2 hv; hv.x = v0; hv.y = v1;
  *(float2*)(h2 + (size_t)n*OUT2C + 2*l) = hv;
  float pp = v0*w_gate[2*l] + v1*w_gate[2*l+1];
  #pragma unroll
  for (int off = 32; off; off >>= 1) pp += __shfl_xor(pp, off);
  if (l == 0) wnode[n] = 1.f/(1.f + expf(-(pp + b_gate[0])));
}

// one block per graph: weighted-sum + max readout, bf16 out into xcb[:, 0:256]
__global__ __launch_bounds__(128) void k_readout(const float* __restrict__ h2,
                                                 const float* __restrict__ wnode,
                                                 const int* __restrict__ batch,
                                                 ushort_t* __restrict__ xcb){
  __shared__ int lohi[2];
  int g = blockIdx.x, t = threadIdx.x;
  if (t == 0){
    int lo = 0, hi = N_NODESC;
    while (lo < hi){ int mid = (lo+hi) >> 1; if (batch[mid] < g) lo = mid+1; else hi = mid; }
    lohi[0] = lo;
    int lo2 = lo; hi = N_NODESC;
    while (lo2 < hi){ int mid = (lo2+hi) >> 1; if (batch[mid] < g+1) lo2 = mid+1; else hi = mid; }
    lohi[1] = lo2;
  }
  __syncthreads();
  int lo = lohi[0], hi = lohi[1];
  float sum = 0.f, mx = 0.f;
  for (int n = lo; n < hi; n++){
    float v = h2[(size_t)n*OUT2C + t];
    sum += v * wnode[n];
    mx = fmaxf(mx, v);
  }
  xcb[(size_t)g*512 + t] = f2bf(sum);
  xcb[(size_t)g*512 + 128 + t] = f2bf(mx);
}

__global__ void k_final(const ushort_t* __restrict__ f2b, const float* __restrict__ W_out,
                        const float* __restrict__ b_out, float* __restrict__ out){
  int g = blockIdx.x*4 + (threadIdx.x >> 6);
  int l = threadIdx.x & 63;
  if (g >= N_GRAPHSC) return;
  float s = 0.f;
  #pragma unroll
  for (int k = 0; k < 4; k++) s += bf2f(f2b[(size_t)g*256 + l + 64*k]) * W_out[l + 64*k];
  #pragma unroll
  for (int off = 32; off; off >>= 1) s += __shfl_xor(s, off);
  if (l == 0) out[g] = s + b_out[0];
}

extern "C" void kernel_launch(void* const* d_in, const int* in_sizes, int n_in,
                              void* d_out, int out_size, void* d_ws, size_t ws_size,
                              hipStream_t stream) {
  const float* x      = (const float*)d_in[0];
  const int*   ei     = (const int*)d_in[1];
  const int*   batch  = (const int*)d_in[2];
  const float* target = (const float*)d_in[3];
  const float* W1     = (const float*)d_in[4];
  const float* a_src1 = (const float*)d_in[5];
  const float* a_dst1 = (const float*)d_in[6];
  const float* b1     = (const float*)d_in[7];
  const float* W2     = (const float*)d_in[8];
  const float* a_src2 = (const float*)d_in[9];
  const float* a_dst2 = (const float*)d_in[10];
  const float* b2     = (const float*)d_in[11];
  const float* w_gate = (const float*)d_in[12];
  const float* b_gate = (const float*)d_in[13];
  const float* W_xt   = (const float*)d_in[14];
  const float* b_xt   = (const float*)d_in[15];
  const float* W_fc1  = (const float*)d_in[16];
  const float* b_fc1  = (const float*)d_in[17];
  const float* W_fc2  = (const float*)d_in[18];
  const float* b_fc2  = (const float*)d_in[19];
  const float* W_out  = (const float*)d_in[20];
  const float* b_out  = (const float*)d_in[21];
  float* out = (float*)d_out;

  // ---- adaptive chunking (C=1 when workspace allows) ----
  const size_t MB = (size_t)1 << 20;
  int C;
  if      (ws_size >= 245*MB) C = 1;
  else if (ws_size >= 150*MB) C = 2;
  else                        C = 4;
  const int R = N_NODESC / C;          // R and R/4 integral for C in {1,2,4}

  char* p = (char*)d_ws;
  auto carve = [&](size_t bytes) -> char* {
    char* r = p; p += (bytes + 255) & ~(size_t)255; return r;
  };
  int*   deg    = (int*)  carve((size_t)N_NODESC*4);
  int*   rowptr = (int*)  carve((size_t)(N_NODESC+1)*4);
  int*   cnt    = (int*)  carve((size_t)N_NODESC*4);
  int*   esrc   = (int*)  carve((size_t)E_TOTC*4);
  int*   bsum   = (int*)  carve(128*4);
  float* Wa1    = (float*)carve((size_t)F_INC*20*4);
  float* att1   = (float*)carve((size_t)N_NODESC*20*4);
  float* stat1  = (float*)carve((size_t)N_NODESC*20*4);
  float* att2   = (float*)carve((size_t)N_NODESC*2*4);
  float* stat2  = (float*)carve((size_t)N_NODESC*2*4);
  float* ealpha = (float*)carve((size_t)E_TOTC*4);
  float* wnode  = (float*)carve((size_t)N_NODESC*4);
  ushort_t* W1t   = (ushort_t*)carve((size_t)HEADS1C*80*96*2);
  ushort_t* W2f   = (ushort_t*)carve((size_t)HEADS1C*128*96*2);
  ushort_t* Wxtt  = (ushort_t*)carve((size_t)256*1280*2);
  ushort_t* Wfc1t = (ushort_t*)carve((size_t)1024*512*2);
  ushort_t* Wfc2t = (ushort_t*)carve((size_t)256*1024*2);
  ushort_t* tb    = (ushort_t*)carve((size_t)N_GRAPHSC*1280*2);
  ushort_t* h2pre = (ushort_t*)carve((size_t)N_NODESC*OUT2C*2);
  ushort_t* xcb   = (ushort_t*)carve((size_t)N_GRAPHSC*512*2);
  ushort_t* f1b   = (ushort_t*)carve((size_t)N_GRAPHSC*1024*2);
  ushort_t* f2b   = (ushort_t*)carve((size_t)N_GRAPHSC*256*2);
  size_t big_bytes = (size_t)R*F1C*2 + 4096;            // zc (bf16) + overread slack
  size_t h2_bytes  = (size_t)N_NODESC*OUT2C*4;          // h2 (fp32)
  char*  BIG = carve(big_bytes > h2_bytes ? big_bytes : h2_bytes);
  ushort_t* zc  = (ushort_t*)BIG;
  float* h2 = (float*)BIG;   // overlays zc AFTER the fused layer-1/2 pass is done

  hipMemsetAsync(deg, 0, (size_t)N_NODESC*4, stream);
  hipMemsetAsync(cnt, 0, (size_t)N_NODESC*4, stream);

  // CSR by destination (self-loops appended)
  k_deg<<<(E_TOTC+255)/256, 256, 0, stream>>>(ei, deg);
  int nb = (N_NODESC + 1023)/1024;
  k_scan1<<<nb, 1024, 0, stream>>>(deg, rowptr, bsum);
  k_scan2<<<1, 64, 0, stream>>>(bsum, rowptr, nb);
  k_scan3<<<nb, 1024, 0, stream>>>(rowptr, bsum);
  k_scatter<<<(E_TOTC+255)/256, 256, 0, stream>>>(ei, rowptr, cnt, esrc);

  // weight prep (bf16 transposed, zero-padded) + target cast
  k_prepW1<<<(HEADS1C*80*96+255)/256, 256, 0, stream>>>(W1, W1t);
  k_prepW2f<<<(HEADS1C*128*96+255)/256, 256, 0, stream>>>(W2, W2f);
  k_prepWt<<<(256*1280+255)/256, 256, 0, stream>>>(W_xt, Wxtt, 1280, 256, 1280);
  k_prepWt<<<(1024*512+255)/256, 256, 0, stream>>>(W_fc1, Wfc1t, 512, 1024, 512);
  k_prepWt<<<(256*1024+255)/256, 256, 0, stream>>>(W_fc2, Wfc2t, 1024, 256, 1024);
  k_cast_bf<<<((N_GRAPHSC*1280)+255)/256, 256, 0, stream>>>(target, tb, N_GRAPHSC*1280);

  // layer-1 attention logits via folded weights (per-node kernels)
  k_wa1<<<(F_INC*20+255)/256, 256, 0, stream>>>(W1, a_src1, a_dst1, Wa1);
  k_att1<<<(N_NODESC+255)/256, 256, 0, stream>>>(x, Wa1, att1);
  k_stats1<<<(N_NODESC+255)/256, 256, 0, stream>>>(att1, rowptr, esrc, stat1);

  // layer-1 (chunked): agg -> zc; FUSED GEMM+elu+projection+att2 -> h2pre,att2
  for (int c = 0; c < C; c++){
    int base = c*R;
    k_agg1<<<R/4, 256, 0, stream>>>(x, att1, stat1, rowptr, esrc, zc, base);
    mfma_fused12<<<(R+63)/64, 256, 0, stream>>>(
        zc, W1t, b1, W2f, h2pre + (size_t)base*OUT2C, att2 + (size_t)base*2,
        a_src2, a_dst2, R);
  }

  // layer-2 softmax stats (+ per-edge alpha) + aggregation
  k_stats2<<<(N_NODESC+255)/256, 256, 0, stream>>>(att2, rowptr, esrc, stat2, ealpha);
  k_agg2<<<(N_NODESC+3)/4, 256, 0, stream>>>(h2pre, ealpha, rowptr, esrc,
                                             b2, w_gate, b_gate, h2, wnode);

  // readout (bf16) + MLP head via MFMA (K multiples of 32 -> KVAL=32, no masks)
  k_readout<<<N_GRAPHSC, 128, 0, stream>>>(h2, wnode, batch, xcb);
  mfma_gemm<128,8,1280,32,0,true><<<dim3(N_GRAPHSC/64, 256/128, 1), 256, 0, stream>>>(
      tb, Wxtt, b_xt, xcb + 256, N_GRAPHSC, 256, 1280, 512, 0,0,0,0);
  mfma_gemm<128,8,512,32,1,true><<<dim3(N_GRAPHSC/64, 1024/128, 1), 256, 0, stream>>>(
      xcb, Wfc1t, b_fc1, f1b, N_GRAPHSC, 1024, 512, 1024, 0,0,0,0);
  mfma_gemm<128,8,1024,32,1,true><<<dim3(N_GRAPHSC/64, 256/128, 1), 256, 0, stream>>>(
      f1b, Wfc2t, b_fc2, f2b, N_GRAPHSC, 256, 1024, 256, 0,0,0,0);
  k_final<<<(N_GRAPHSC+3)/4, 256, 0, stream>>>(f2b, W_out, b_out, out);
}

// Round 13
// 618.782 us; speedup vs baseline: 1.0682x; 1.0682x over previous
//
#include <hip/hip_runtime.h>
#include <cstdint>
#include <cstddef>

#define N_NODESC 100000
#define N_EDGESC 400000
#define N_GRAPHSC 2048
#define F_INC 78
#define HEADS1C 10
#define D1C 78           // per-head out dim, layer 1
#define F1C 780          // HEADS1C * D1C
#define OUT2C 128
#define E_TOTC (N_EDGESC + N_NODESC)   // 500000 edges incl. self-loops

typedef unsigned short ushort_t;
typedef __attribute__((ext_vector_type(8))) short short8;
typedef __attribute__((ext_vector_type(4))) float f32x4;
typedef __attribute__((ext_vector_type(4))) unsigned int uint4v;
union U4S8 { uint4v u; short8 s; };

static __device__ __forceinline__ float lrelu(float x){ return x > 0.f ? x : 0.2f*x; }

// fast ELU: v_exp_f32-based (expm1f was ~25 VALU inst; __expf is 2).
static __device__ __forceinline__ float elu_fast(float v){
  return (v > 0.f) ? v : (__expf(v) - 1.0f);
}

// LDS-only barrier: __syncthreads on gfx950 drains vmcnt(0) too, which kills
// in-flight global prefetches.  This waits LDS ops only and leaves global
// loads in flight across the barrier.
static __device__ __forceinline__ void bar_lds(){
  asm volatile("s_waitcnt lgkmcnt(0)" ::: "memory");
  __builtin_amdgcn_s_barrier();
}

// bf16 helpers (round-to-nearest-even)
static __device__ __forceinline__ unsigned short f2bf(float f){
  unsigned int u = __float_as_uint(f);
  unsigned int r = (u + 0x7fffu + ((u >> 16) & 1u)) >> 16;
  return (unsigned short)r;
}
static __device__ __forceinline__ float bf2f(unsigned short h){
  return __uint_as_float(((unsigned int)h) << 16);
}

// ---------------- CSR build ----------------
__global__ void k_deg(const int* __restrict__ ei, int* __restrict__ deg){
  int e = blockIdx.x*256 + threadIdx.x;
  if (e >= E_TOTC) return;
  int dst = (e < N_EDGESC) ? ei[N_EDGESC + e] : (e - N_EDGESC);
  atomicAdd(&deg[dst], 1);
}

__global__ __launch_bounds__(1024) void k_scan1(const int* __restrict__ deg,
                                                int* __restrict__ rowptr,
                                                int* __restrict__ bsum){
  __shared__ int s[1024];
  int t = threadIdx.x, i = blockIdx.x*1024 + t;
  int v = (i < N_NODESC) ? deg[i] : 0;
  s[t] = v; __syncthreads();
  for (int d = 1; d < 1024; d <<= 1){
    int xv = (t >= d) ? s[t-d] : 0;
    __syncthreads();
    s[t] += xv;
    __syncthreads();
  }
  if (i < N_NODESC) rowptr[i+1] = s[t];
  if (t == 1023) bsum[blockIdx.x] = s[t];
}

__global__ void k_scan2(int* __restrict__ bsum, int* __restrict__ rowptr, int nb){
  if (threadIdx.x == 0 && blockIdx.x == 0){
    int run = 0;
    for (int b = 0; b < nb; b++){ int v = bsum[b]; bsum[b] = run; run += v; }
    rowptr[0] = 0;
  }
}

__global__ __launch_bounds__(1024) void k_scan3(int* __restrict__ rowptr,
                                                const int* __restrict__ bsum){
  int i = blockIdx.x*1024 + threadIdx.x;
  if (i < N_NODESC) rowptr[i+1] += bsum[blockIdx.x];
}

__global__ void k_scatter(const int* __restrict__ ei, const int* __restrict__ rowptr,
                          int* __restrict__ cnt, int* __restrict__ esrc){
  int e = blockIdx.x*256 + threadIdx.x;
  if (e >= E_TOTC) return;
  int src, dst;
  if (e < N_EDGESC){ src = ei[e]; dst = ei[N_EDGESC + e]; }
  else { src = dst = e - N_EDGESC; }
  int pos = rowptr[dst] + atomicAdd(&cnt[dst], 1);
  esrc[pos] = src;
}

// ---------------- layer-1 attention logit precompute ----------------
__global__ void k_wa1(const float* __restrict__ W1, const float* __restrict__ a_src1,
                      const float* __restrict__ a_dst1, float* __restrict__ Wa1){
  int i = blockIdx.x*256 + threadIdx.x;
  if (i >= F_INC*2*HEADS1C) return;
  int d = i / (2*HEADS1C), c = i % (2*HEADS1C);
  const float* a = (c < HEADS1C) ? a_src1 : a_dst1;
  int h = (c < HEADS1C) ? c : c - HEADS1C;
  float s = 0.f;
  for (int j = 0; j < D1C; j++) s += W1[d*F1C + h*D1C + j] * a[h*D1C + j];
  Wa1[d*(2*HEADS1C) + c] = s;
}

// one thread per node; acc[20] in regs; x read once via float2.
__global__ __launch_bounds__(256) void k_att1(const float* __restrict__ x,
                                              const float* __restrict__ Wa1,
                                              float* __restrict__ att1){
  int n = blockIdx.x*256 + threadIdx.x;
  if (n >= N_NODESC) return;
  const float* xr = x + (size_t)n*F_INC;
  float acc[20];
  #pragma unroll
  for (int c = 0; c < 20; c++) acc[c] = 0.f;
  for (int d0 = 0; d0 < F_INC; d0 += 2){
    float2 xv = *(const float2*)(xr + d0);
    const float* w0 = Wa1 + d0*20;
    #pragma unroll
    for (int c = 0; c < 20; c++)
      acc[c] += xv.x*w0[c] + xv.y*w0[20 + c];
  }
  float* o = att1 + (size_t)n*20;
  #pragma unroll
  for (int j = 0; j < 10; j++){
    float2 ov; ov.x = acc[2*j]; ov.y = acc[2*j+1];
    *(float2*)(o + 2*j) = ov;
  }
}

// one thread per node, all 10 heads at once; float2-vectorized gathers.
__global__ __launch_bounds__(256) void k_stats1(const float* __restrict__ att1,
                                                const int* __restrict__ rowptr,
                                                const int* __restrict__ esrc,
                                                float* __restrict__ stat1){
  int n = blockIdx.x*256 + threadIdx.x;
  if (n >= N_NODESC) return;
  float ad[10];
  {
    const float* a = att1 + (size_t)n*20 + 10;
    #pragma unroll
    for (int j = 0; j < 5; j++){
      float2 v = *(const float2*)(a + 2*j);
      ad[2*j] = v.x; ad[2*j+1] = v.y;
    }
  }
  int b = rowptr[n], e = rowptr[n+1];
  float m[10];
  #pragma unroll
  for (int h = 0; h < 10; h++) m[h] = -1e30f;
  for (int p = b; p < e; p += 2){
    int s0 = esrc[p];
    int s1 = esrc[(p+1 < e) ? p+1 : p];
    float2 v0[5], v1[5];
    #pragma unroll
    for (int j = 0; j < 5; j++) v0[j] = *(const float2*)(att1 + (size_t)s0*20 + 2*j);
    #pragma unroll
    for (int j = 0; j < 5; j++) v1[j] = *(const float2*)(att1 + (size_t)s1*20 + 2*j);
    #pragma unroll
    for (int h = 0; h < 10; h++){
      float a0 = (h & 1) ? v0[h>>1].y : v0[h>>1].x;
      m[h] = fmaxf(m[h], lrelu(a0 + ad[h]));
    }
    if (p+1 < e){
      #pragma unroll
      for (int h = 0; h < 10; h++){
        float a1 = (h & 1) ? v1[h>>1].y : v1[h>>1].x;
        m[h] = fmaxf(m[h], lrelu(a1 + ad[h]));
      }
    }
  }
  float den[10];
  #pragma unroll
  for (int h = 0; h < 10; h++) den[h] = 0.f;
  for (int p = b; p < e; p += 2){
    int s0 = esrc[p];
    int s1 = esrc[(p+1 < e) ? p+1 : p];
    float2 v0[5], v1[5];
    #pragma unroll
    for (int j = 0; j < 5; j++) v0[j] = *(const float2*)(att1 + (size_t)s0*20 + 2*j);
    #pragma unroll
    for (int j = 0; j < 5; j++) v1[j] = *(const float2*)(att1 + (size_t)s1*20 + 2*j);
    #pragma unroll
    for (int h = 0; h < 10; h++){
      float a0 = (h & 1) ? v0[h>>1].y : v0[h>>1].x;
      den[h] += expf(lrelu(a0 + ad[h]) - m[h]);
    }
    if (p+1 < e){
      #pragma unroll
      for (int h = 0; h < 10; h++){
        float a1 = (h & 1) ? v1[h>>1].y : v1[h>>1].x;
        den[h] += expf(lrelu(a1 + ad[h]) - m[h]);
      }
    }
  }
  float* o = stat1 + (size_t)n*20;
  #pragma unroll
  for (int h = 0; h < 10; h++){
    o[h] = m[h];
    o[10 + h] = 1.f/(den[h] + 1e-16f);
  }
}

// LDS-free aggregation (v9): lane = feature d; coalesced x gathers, alpha
// broadcast via shfl; 4 independent waves per block, zero LDS/barriers.
__global__ __launch_bounds__(256) void k_agg1(
    const float* __restrict__ x, const float* __restrict__ att1,
    const float* __restrict__ stat1, const int* __restrict__ rowptr,
    const int* __restrict__ esrc, ushort_t* __restrict__ zc, int base){
  int wv = threadIdx.x >> 6;
  int l  = threadIdx.x & 63;
  int nl = blockIdx.x*4 + wv;          // chunk-local node index (grid = R/4)
  int n  = base + nl;
  int b = rowptr[n], e = rowptr[n+1];
  float ad = 0.f, mm = 0.f, rd = 0.f;
  if (l < HEADS1C){
    ad = att1[n*20 + 10 + l];
    mm = stat1[n*20 + l];
    rd = stat1[n*20 + 10 + l];
  }
  float acc0[10], acc1[10];
  #pragma unroll
  for (int h = 0; h < 10; h++){ acc0[h] = 0.f; acc1[h] = 0.f; }
  bool lo14 = (l < 14);
  for (int p = b; p < e; p += 4){
    int c = e - p; if (c > 4) c = 4;
    int ss[4];
    #pragma unroll
    for (int j = 0; j < 4; j++) ss[j] = esrc[p + (j < c ? j : 0)];
    float alv[4];
    #pragma unroll
    for (int j = 0; j < 4; j++){
      float av = (l < HEADS1C) ? att1[ss[j]*20 + l] : 0.f;
      float ev = lrelu(av + ad);
      alv[j] = (j < c) ? expf(ev - mm) * rd : 0.f;
    }
    float xv0[4], xv1[4];
    #pragma unroll
    for (int j = 0; j < 4; j++){
      const float* xr = x + (size_t)ss[j]*F_INC;
      xv0[j] = xr[l];
      xv1[j] = lo14 ? xr[64 + l] : 0.f;
    }
    #pragma unroll
    for (int h = 0; h < 10; h++){
      float a0 = __shfl(alv[0], h);
      float a1 = __shfl(alv[1], h);
      float a2 = __shfl(alv[2], h);
      float a3 = __shfl(alv[3], h);
      float s0 = a0*xv0[0] + a1*xv0[1] + a2*xv0[2] + a3*xv0[3];
      float s1 = a0*xv1[0] + a1*xv1[1] + a2*xv1[2] + a3*xv1[3];
      acc0[h] += s0;
      acc1[h] += s1;
    }
  }
  ushort_t* zr = zc + (size_t)nl*F1C;
  #pragma unroll
  for (int h = 0; h < 10; h++){
    zr[h*78 + l] = f2bf(acc0[h]);
    if (lo14) zr[h*78 + 64 + l] = f2bf(acc1[h]);
  }
}

// ---------------- weight pre-transpose (zero-padded bf16) ----------------
__global__ void k_prepW1(const float* __restrict__ W1, ushort_t* __restrict__ W1t){
  // W1t[h][n(80)][k(96)] = bf16(W1[k][h*78+n]) with zero pad
  int i = blockIdx.x*256 + threadIdx.x;
  if (i >= HEADS1C*80*96) return;
  int h = i / (80*96), rem = i % (80*96), n = rem / 96, k = rem % 96;
  float v = (n < D1C && k < F_INC) ? W1[(size_t)k*F1C + h*D1C + n] : 0.f;
  W1t[i] = f2bf(v);
}

// W2f[h][n(128)][k(96)] = bf16(W2[h*78+k][n]) with zero pad in k (78..95)
__global__ void k_prepW2f(const float* __restrict__ W2, ushort_t* __restrict__ W2f){
  int i = blockIdx.x*256 + threadIdx.x;
  if (i >= HEADS1C*128*96) return;
  int h = i / (128*96), rem = i % (128*96), n = rem / 96, k = rem % 96;
  float v = (k < D1C) ? W2[(size_t)(h*D1C + k)*OUT2C + n] : 0.f;
  W2f[i] = f2bf(v);
}

// generic: Wt[n][k(KB)] = bf16(W[k][n]) zero-padded in k
__global__ void k_prepWt(const float* __restrict__ W, ushort_t* __restrict__ Wt,
                         int Kdim, int Ndim, int KB){
  int i = blockIdx.x*256 + threadIdx.x;
  if (i >= Ndim*KB) return;
  int n = i / KB, k = i % KB;
  float v = (k < Kdim) ? W[(size_t)k*Ndim + n] : 0.f;
  Wt[i] = f2bf(v);
}

__global__ void k_cast_bf(const float* __restrict__ in, ushort_t* __restrict__ o, int n){
  int i = blockIdx.x*256 + threadIdx.x;
  if (i < n) o[i] = f2bf(in[i]);
}

// ---------------- MFMA bf16 GEMM: C[M,N] = act(A @ Bt^T + bias), bf16 out ---
template<int BN, int NT, int KB, int KVAL, int ACT, bool HASBIAS>
__global__ __launch_bounds__(256) void mfma_gemm(
    const ushort_t* __restrict__ A, const ushort_t* __restrict__ Bt,
    const float* __restrict__ bias, ushort_t* __restrict__ C,
    int M, int N, int lda, int ldc,
    int zsA, int zsBt, int zsC, int zsBias)
{
  __shared__ unsigned int As[64][20];   // 64 rows x 32 bf16 (+pad)
  __shared__ unsigned int Bs[BN][20];
  int z = blockIdx.z;
  A += (size_t)z*zsA; Bt += (size_t)z*zsBt; C += (size_t)z*zsC;
  const float* bz = HASBIAS ? (bias + (size_t)z*zsBias) : nullptr;
  int m0 = blockIdx.x*64;
  int n0 = blockIdx.y*BN;
  int t = threadIdx.x;
  int w = t >> 6, lane = t & 63;
  int q = lane >> 4, li = lane & 15;
  f32x4 acc[NT];
  #pragma unroll
  for (int i = 0; i < NT; i++) acc[i] = (f32x4){0.f,0.f,0.f,0.f};

  int am = t >> 2;           // staged row 0..63
  int ak0 = (t & 3)*8;       // short col base 0,8,16,24
  int gm = m0 + am;
  bool rv = (gm < M);

  #pragma unroll
  for (int ki = 0; ki < KB/32; ki++){
    const int kt = ki*32;
    int nv;
    if (ki == KB/32 - 1){
      int d = KVAL - ak0; nv = d < 0 ? 0 : (d > 8 ? 8 : d);
    } else nv = 8;
    {
      unsigned u0=0u, u1=0u, u2=0u, u3=0u;
      if (rv && nv > 0){
        const unsigned int* ap = (const unsigned int*)(A + (size_t)gm*lda + kt + ak0);
        u0 = ap[0]; u1 = ap[1]; u2 = ap[2]; u3 = ap[3];
        int ndw = nv >> 1;
        if (ndw < 4) u3 = 0u;
        if (ndw < 3) u2 = 0u;
        if (ndw < 2) u1 = 0u;
      }
      int c0 = (t & 3)*4;
      As[am][c0] = u0; As[am][c0+1] = u1; As[am][c0+2] = u2; As[am][c0+3] = u3;
    }
    for (int g = t; g < BN*4; g += 256){
      int n = g >> 2, c0 = (g & 3)*4;
      const unsigned int* bp = (const unsigned int*)(Bt + (size_t)(n0 + n)*KB + kt + c0*2);
      Bs[n][c0] = bp[0]; Bs[n][c0+1] = bp[1]; Bs[n][c0+2] = bp[2]; Bs[n][c0+3] = bp[3];
    }
    __syncthreads();
    U4S8 a; a.u = *(const uint4v*)&As[w*16 + li][q*4];
    #pragma unroll
    for (int nt = 0; nt < NT; nt++){
      U4S8 b; b.u = *(const uint4v*)&Bs[nt*16 + li][q*4];
      acc[nt] = __builtin_amdgcn_mfma_f32_16x16x32_bf16(a.s, b.s, acc[nt], 0, 0, 0);
    }
    __syncthreads();
  }
  #pragma unroll
  for (int nt = 0; nt < NT; nt++){
    int col = n0 + nt*16 + li;
    if (col >= N) continue;
    float bv = HASBIAS ? bz[col] : 0.f;
    #pragma unroll
    for (int r = 0; r < 4; r++){
      int gmr = m0 + w*16 + q*4 + r;
      if (gmr >= M) continue;
      float v = acc[nt][r] + bv;
      if (ACT == 1) v = fmaxf(v, 0.f);
      else if (ACT == 2) v = (v > 0.f) ? v : (__expf(v) - 1.0f);
      C[(size_t)gmr*ldc + col] = f2bf(v);
    }
  }
}

// ---------------- FUSED layer-1 GEMM + projection (v11, restored) ----------
// h2pre[m, 0:128] = sum_h  elu( zc[m, h*78:+78] @ W1h + b1_h )  @  W2[h*78:+78, 0:128]
// + fused att2 logits from the bf16-rounded h2pre values.
// Split weight buffers Bs1/Bs2 (flat stride 48 — stride-49 "fix" REGRESSED:
// conflicts 1.05e7 -> 2.54e7, 104 -> 164us; b128 LDS reads don't follow the
// naive per-dword bank model), 2 bar_lds/head, T14 reg staging, one-head-
// ahead A prefetch, (256,3) reg cap.
__global__ __launch_bounds__(256, 3) void mfma_fused12(
    const ushort_t* __restrict__ zc, const ushort_t* __restrict__ W1t,
    const float* __restrict__ b1, const ushort_t* __restrict__ W2f,
    ushort_t* __restrict__ h2pre, float* __restrict__ att2,
    const float* __restrict__ a_src2, const float* __restrict__ a_dst2,
    int M)
{
  __shared__ unsigned int Bs1[80*48];   // W1t[h] flat: 80 rows x 48 dw
  __shared__ unsigned int Bs2[128*48];  // W2f[h] flat: 128 rows x 48 dw
  __shared__ unsigned int Ts[64][52];   // T bf16 (96 shorts + pad), wave-private rows
  int m0 = blockIdx.x*64;
  int t = threadIdx.x;
  int w = t >> 6, lane = t & 63;
  int q = lane >> 4, li = lane & 15;

  const uint4v* w1v = (const uint4v*)W1t;   // [h*960 + g] 16B groups
  const uint4v* w2v = (const uint4v*)W2f;   // [h*1536 + g]

  // ---- staging-register helpers (T14 split: issue early, ds_write late) ----
  uint4v rw1[4], rw2[6];
  auto issueW1 = [&](int h){
    #pragma unroll
    for (int g0 = 0; g0 < 4; g0++){
      int g = t + g0*256;
      if (g < 960) rw1[g0] = w1v[(size_t)h*960 + g];
    }
  };
  auto writeW1 = [&](){
    #pragma unroll
    for (int g0 = 0; g0 < 4; g0++){
      int g = t + g0*256;
      if (g < 960) *(uint4v*)&Bs1[g*4] = rw1[g0];
    }
  };
  auto issueW2 = [&](int h){
    #pragma unroll
    for (int g0 = 0; g0 < 6; g0++)
      rw2[g0] = w2v[(size_t)h*1536 + t + g0*256];
  };
  auto writeW2 = [&](){
    #pragma unroll
    for (int g0 = 0; g0 < 6; g0++){
      int g = t + g0*256;
      *(uint4v*)&Bs2[g*4] = rw2[g0];
    }
  };

  f32x4 acc2[8];
  #pragma unroll
  for (int i = 0; i < 8; i++) acc2[i] = (f32x4){0.f,0.f,0.f,0.f};

  issueW1(0);                           // both head-0 weight tiles in flight
  issueW2(0);

  // zero Ts pad dwords 39..47 (cols 78..95) once (read in stage-2 ki=2;
  // published by the prologue barrier)
  for (int i = t; i < 64*9; i += 256) Ts[i/9][39 + i%9] = 0u;

  // this lane's A row: m0 + w*16 + li; k-chunk q (shorts q*8..q*8+7 per 32-k tile)
  int ar = m0 + w*16 + li;
  bool rv = (ar < M);
  const unsigned int* abase = (const unsigned int*)(zc + (size_t)ar*F1C);

  // A-fragment loader for head h: af[ki], k = ki*32 + q*8 (head slice is 78 wide)
  auto lda = [&](int h, uint4v* af){
    af[0] = (uint4v){0u,0u,0u,0u};
    af[1] = (uint4v){0u,0u,0u,0u};
    af[2] = (uint4v){0u,0u,0u,0u};
    if (rv){
      const unsigned int* p = abase + h*39 + q*4;    // h*78 shorts = h*39 dwords
      af[0][0]=p[0];  af[0][1]=p[1];  af[0][2]=p[2];  af[0][3]=p[3];
      af[1][0]=p[16]; af[1][1]=p[17]; af[1][2]=p[18]; af[1][3]=p[19];
      if (q < 2){                                    // k 64..79 only (78,79 zeroed)
        af[2][0]=p[32]; af[2][1]=p[33]; af[2][2]=p[34]; af[2][3]=p[35];
        if (q == 1) af[2][3] = 0u;
      }
    }
  };

  uint4v acur[3], anxt[3];
  lda(0, acur);

  writeW1();                            // Bs1 <- W1[0] (vmcnt wait, once)
  bar_lds();                            // Bs1 + Ts-pad visible

  #pragma unroll 1
  for (int h = 0; h < HEADS1C; h++){
    int hn = (h+1 < HEADS1C) ? h+1 : 0;
    writeW2();                          // Bs2 <- W2[h]; rw2 dies (stage-1 reads Bs1)
    issueW1(hn);                        // W1[h+1] -> regs, in flight over stage-1
    // per-head bias: 5 per lane (cols nt*16+li)
    float bv[5];
    #pragma unroll
    for (int nt = 0; nt < 5; nt++){
      int col = nt*16 + li;
      bv[nt] = (col < D1C) ? b1[h*D1C + col] : 0.f;
    }

    // stage-1 MFMA: T(64x80) = zc_h @ W1h (A from registers, B from Bs1)
    f32x4 acc1[5];
    #pragma unroll
    for (int i = 0; i < 5; i++) acc1[i] = (f32x4){0.f,0.f,0.f,0.f};
    #pragma unroll
    for (int ki = 0; ki < 3; ki++){
      U4S8 a; a.u = acur[ki];
      #pragma unroll
      for (int nt = 0; nt < 5; nt++){
        U4S8 b; b.u = *(const uint4v*)&Bs1[(nt*16 + li)*48 + ki*16 + q*4];
        acc1[nt] = __builtin_amdgcn_mfma_f32_16x16x32_bf16(a.s, b.s, acc1[nt], 0, 0, 0);
      }
    }
    // bias + fast elu -> bf16 into Ts (wave-private rows)
    #pragma unroll
    for (int nt = 0; nt < 5; nt++){
      int col = nt*16 + li;
      #pragma unroll
      for (int r = 0; r < 4; r++){
        int row = w*16 + q*4 + r;
        float v = elu_fast(acc1[nt][r] + bv[nt]);
        ((ushort_t*)&Ts[row][0])[col] = f2bf(v);
      }
    }
    // prefetch next head's A frags (zc, L3) — stays in flight across barriers
    lda(hn, anxt);

    bar_lds();                          // stage-1 Bs1 reads done; Bs2+Ts visible
    writeW1();                          // Bs1 <- W1[h+1]; rw1 dies (stage-2 reads Bs2)
    issueW2(hn);                        // W2[h+1] -> regs, in flight over stage-2

    // stage-2 MFMA: acc2 += T @ W2f[h] (A from own Ts rows, B from Bs2)
    #pragma unroll
    for (int ki = 0; ki < 3; ki++){
      U4S8 a; a.u = *(const uint4v*)&Ts[w*16 + li][ki*16 + q*4];
      #pragma unroll
      for (int nt = 0; nt < 8; nt++){
        U4S8 b; b.u = *(const uint4v*)&Bs2[(nt*16 + li)*48 + ki*16 + q*4];
        acc2[nt] = __builtin_amdgcn_mfma_f32_16x16x32_bf16(a.s, b.s, acc2[nt], 0, 0, 0);
      }
    }
    bar_lds();                          // stage-2 Bs2 reads done; Bs1 writes visible
    acur[0] = anxt[0]; acur[1] = anxt[1]; acur[2] = anxt[2];
  }

  // ---- epilogue: h2pre bf16 + fused att2 logits (from bf16-rounded vals) ---
  float as2[8], ad2[8];
  #pragma unroll
  for (int nt = 0; nt < 8; nt++){
    int col = nt*16 + li;
    as2[nt] = a_src2[col];
    ad2[nt] = a_dst2[col];
  }
  #pragma unroll
  for (int r = 0; r < 4; r++){
    int gmr = m0 + w*16 + q*4 + r;
    float p0 = 0.f, p1 = 0.f;
    ushort_t hv[8];
    #pragma unroll
    for (int nt = 0; nt < 8; nt++){
      ushort_t hb = f2bf(acc2[nt][r]);
      float vb = bf2f(hb);
      p0 += vb*as2[nt]; p1 += vb*ad2[nt];
      hv[nt] = hb;
    }
    #pragma unroll
    for (int off = 1; off < 16; off <<= 1){
      p0 += __shfl_xor(p0, off);
      p1 += __shfl_xor(p1, off);
    }
    if (gmr < M){
      #pragma unroll
      for (int nt = 0; nt < 8; nt++)
        h2pre[(size_t)gmr*OUT2C + nt*16 + li] = hv[nt];
      if (li == 0){
        att2[(size_t)gmr*2]     = p0;
        att2[(size_t)gmr*2 + 1] = p1;
      }
    }
  }
}

// per node: max + 1/(sum exp); the den pass writes the UNSCALED per-edge
// exp values inline (they are computed anyway) — k_agg2 scales by rd.
// alpha = ev * rd is the same float product v11 computed -> bitwise identical.
__global__ void k_stats2(const float* __restrict__ att2, const int* __restrict__ rowptr,
                         const int* __restrict__ esrc, float* __restrict__ rstat2,
                         float* __restrict__ ealpha){
  int n = blockIdx.x*256 + threadIdx.x;
  if (n >= N_NODESC) return;
  float ad = att2[n*2+1];
  int b = rowptr[n], e = rowptr[n+1];
  float m = -1e30f;
  for (int p = b; p < e; p += 4){
    int c = e - p; if (c > 4) c = 4;
    float v[4];
    #pragma unroll
    for (int j = 0; j < 4; j++){ int s = esrc[p + (j < c ? j : 0)]; v[j] = att2[s*2]; }
    #pragma unroll
    for (int j = 0; j < 4; j++) if (j < c) m = fmaxf(m, lrelu(v[j] + ad));
  }
  float den = 0.f;
  for (int p = b; p < e; p += 4){
    int c = e - p; if (c > 4) c = 4;
    float v[4];
    #pragma unroll
    for (int j = 0; j < 4; j++){ int s = esrc[p + (j < c ? j : 0)]; v[j] = att2[s*2]; }
    #pragma unroll
    for (int j = 0; j < 4; j++){
      if (j < c){
        float ev = expf(lrelu(v[j] + ad) - m);
        den += ev;
        ealpha[p + j] = ev;
      }
    }
  }
  rstat2[n] = 1.f/(den + 1e-16f);
}

// wave per node; per-edge exp loaded precomputed (wave-uniform ->
// scalarizable), scaled by the node's rd; inner loop is pure gather + FMA.
__global__ void k_agg2(const ushort_t* __restrict__ h2pre,
                       const float* __restrict__ ealpha,
                       const float* __restrict__ rstat2,
                       const int* __restrict__ rowptr,
                       const int* __restrict__ esrc, const float* __restrict__ b2,
                       const float* __restrict__ w_gate, const float* __restrict__ b_gate,
                       float* __restrict__ h2, float* __restrict__ wnode){
  int n = blockIdx.x*4 + (threadIdx.x >> 6);
  int l = threadIdx.x & 63;
  if (n >= N_NODESC) return;
  float rd = rstat2[n];
  int b = rowptr[n], e = rowptr[n+1];
  float a0 = 0.f, a1 = 0.f;
  for (int p = b; p < e; p += 4){
    int c = e - p; if (c > 4) c = 4;
    int ss[4]; float al[4];
    #pragma unroll
    for (int j = 0; j < 4; j++) ss[j] = esrc[p + (j < c ? j : 0)];
    #pragma unroll
    for (int j = 0; j < 4; j++) al[j] = (j < c) ? ealpha[p + j] * rd : 0.f;
    unsigned u[4];
    #pragma unroll
    for (int j = 0; j < 4; j++) u[j] = *(const unsigned*)(h2pre + (size_t)ss[j]*OUT2C + 2*l);
    #pragma unroll
    for (int j = 0; j < 4; j++){
      a0 += al[j] * bf2f((ushort_t)(u[j] & 0xffffu));
      a1 += al[j] * bf2f((ushort_t)(u[j] >> 16));
    }
  }
  float v0 = fmaxf(a0 + b2[2*l],   0.f);
  float v1 = fmaxf(a1 + b2[2*l+1], 0.f);
  float2 hv; hv.x = v0; hv.y = v1;
  *(float2*)(h2 + (size_t)n*OUT2C + 2*l) = hv;
  float pp = v0*w_gate[2*l] + v1*w_gate[2*l+1];
  #pragma unroll
  for (int off = 32; off; off >>= 1) pp += __shfl_xor(pp, off);
  if (l == 0) wnode[n] = 1.f/(1.f + expf(-(pp + b_gate[0])));
}

// one block per graph: weighted-sum + max readout, bf16 out into xcb[:, 0:256]
__global__ __launch_bounds__(128) void k_readout(const float* __restrict__ h2,
                                                 const float* __restrict__ wnode,
                                                 const int* __restrict__ batch,
                                                 ushort_t* __restrict__ xcb){
  __shared__ int lohi[2];
  int g = blockIdx.x, t = threadIdx.x;
  if (t == 0){
    int lo = 0, hi = N_NODESC;
    while (lo < hi){ int mid = (lo+hi) >> 1; if (batch[mid] < g) lo = mid+1; else hi = mid; }
    lohi[0] = lo;
    int lo2 = lo; hi = N_NODESC;
    while (lo2 < hi){ int mid = (lo2+hi) >> 1; if (batch[mid] < g+1) lo2 = mid+1; else hi = mid; }
    lohi[1] = lo2;
  }
  __syncthreads();
  int lo = lohi[0], hi = lohi[1];
  float sum = 0.f, mx = 0.f;
  for (int n = lo; n < hi; n++){
    float v = h2[(size_t)n*OUT2C + t];
    sum += v * wnode[n];
    mx = fmaxf(mx, v);
  }
  xcb[(size_t)g*512 + t] = f2bf(sum);
  xcb[(size_t)g*512 + 128 + t] = f2bf(mx);
}

__global__ void k_final(const ushort_t* __restrict__ f2b, const float* __restrict__ W_out,
                        const float* __restrict__ b_out, float* __restrict__ out){
  int g = blockIdx.x*4 + (threadIdx.x >> 6);
  int l = threadIdx.x & 63;
  if (g >= N_GRAPHSC) return;
  float s = 0.f;
  #pragma unroll
  for (int k = 0; k < 4; k++) s += bf2f(f2b[(size_t)g*256 + l + 64*k]) * W_out[l + 64*k];
  #pragma unroll
  for (int off = 32; off; off >>= 1) s += __shfl_xor(s, off);
  if (l == 0) out[g] = s + b_out[0];
}

extern "C" void kernel_launch(void* const* d_in, const int* in_sizes, int n_in,
                              void* d_out, int out_size, void* d_ws, size_t ws_size,
                              hipStream_t stream) {
  const float* x      = (const float*)d_in[0];
  const int*   ei     = (const int*)d_in[1];
  const int*   batch  = (const int*)d_in[2];
  const float* target = (const float*)d_in[3];
  const float* W1     = (const float*)d_in[4];
  const float* a_src1 = (const float*)d_in[5];
  const float* a_dst1 = (const float*)d_in[6];
  const float* b1     = (const float*)d_in[7];
  const float* W2     = (const float*)d_in[8];
  const float* a_src2 = (const float*)d_in[9];
  const float* a_dst2 = (const float*)d_in[10];
  const float* b2     = (const float*)d_in[11];
  const float* w_gate = (const float*)d_in[12];
  const float* b_gate = (const float*)d_in[13];
  const float* W_xt   = (const float*)d_in[14];
  const float* b_xt   = (const float*)d_in[15];
  const float* W_fc1  = (const float*)d_in[16];
  const float* b_fc1  = (const float*)d_in[17];
  const float* W_fc2  = (const float*)d_in[18];
  const float* b_fc2  = (const float*)d_in[19];
  const float* W_out  = (const float*)d_in[20];
  const float* b_out  = (const float*)d_in[21];
  float* out = (float*)d_out;

  // ---- adaptive chunking (C=1 when workspace allows) ----
  const size_t MB = (size_t)1 << 20;
  int C;
  if      (ws_size >= 245*MB) C = 1;
  else if (ws_size >= 150*MB) C = 2;
  else                        C = 4;
  const int R = N_NODESC / C;          // R and R/4 integral for C in {1,2,4}

  char* p = (char*)d_ws;
  auto carve = [&](size_t bytes) -> char* {
    char* r = p; p += (bytes + 255) & ~(size_t)255; return r;
  };
  int*   deg    = (int*)  carve((size_t)N_NODESC*4);
  int*   rowptr = (int*)  carve((size_t)(N_NODESC+1)*4);
  int*   cnt    = (int*)  carve((size_t)N_NODESC*4);
  int*   esrc   = (int*)  carve((size_t)E_TOTC*4);
  int*   bsum   = (int*)  carve(128*4);
  float* Wa1    = (float*)carve((size_t)F_INC*20*4);
  float* att1   = (float*)carve((size_t)N_NODESC*20*4);
  float* stat1  = (float*)carve((size_t)N_NODESC*20*4);
  float* att2   = (float*)carve((size_t)N_NODESC*2*4);
  float* rstat2 = (float*)carve((size_t)N_NODESC*4);
  float* ealpha = (float*)carve((size_t)E_TOTC*4);
  float* wnode  = (float*)carve((size_t)N_NODESC*4);
  ushort_t* W1t   = (ushort_t*)carve((size_t)HEADS1C*80*96*2);
  ushort_t* W2f   = (ushort_t*)carve((size_t)HEADS1C*128*96*2);
  ushort_t* Wxtt  = (ushort_t*)carve((size_t)256*1280*2);
  ushort_t* Wfc1t = (ushort_t*)carve((size_t)1024*512*2);
  ushort_t* Wfc2t = (ushort_t*)carve((size_t)256*1024*2);
  ushort_t* tb    = (ushort_t*)carve((size_t)N_GRAPHSC*1280*2);
  ushort_t* h2pre = (ushort_t*)carve((size_t)N_NODESC*OUT2C*2);
  ushort_t* xcb   = (ushort_t*)carve((size_t)N_GRAPHSC*512*2);
  ushort_t* f1b   = (ushort_t*)carve((size_t)N_GRAPHSC*1024*2);
  ushort_t* f2b   = (ushort_t*)carve((size_t)N_GRAPHSC*256*2);
  size_t big_bytes = (size_t)R*F1C*2 + 4096;            // zc (bf16) + overread slack
  size_t h2_bytes  = (size_t)N_NODESC*OUT2C*4;          // h2 (fp32)
  char*  BIG = carve(big_bytes > h2_bytes ? big_bytes : h2_bytes);
  ushort_t* zc  = (ushort_t*)BIG;
  float* h2 = (float*)BIG;   // overlays zc AFTER the fused layer-1/2 pass is done

  hipMemsetAsync(deg, 0, (size_t)N_NODESC*4, stream);
  hipMemsetAsync(cnt, 0, (size_t)N_NODESC*4, stream);

  // CSR by destination (self-loops appended)
  k_deg<<<(E_TOTC+255)/256, 256, 0, stream>>>(ei, deg);
  int nb = (N_NODESC + 1023)/1024;
  k_scan1<<<nb, 1024, 0, stream>>>(deg, rowptr, bsum);
  k_scan2<<<1, 64, 0, stream>>>(bsum, rowptr, nb);
  k_scan3<<<nb, 1024, 0, stream>>>(rowptr, bsum);
  k_scatter<<<(E_TOTC+255)/256, 256, 0, stream>>>(ei, rowptr, cnt, esrc);

  // weight prep (bf16 transposed, zero-padded) + target cast
  k_prepW1<<<(HEADS1C*80*96+255)/256, 256, 0, stream>>>(W1, W1t);
  k_prepW2f<<<(HEADS1C*128*96+255)/256, 256, 0, stream>>>(W2, W2f);
  k_prepWt<<<(256*1280+255)/256, 256, 0, stream>>>(W_xt, Wxtt, 1280, 256, 1280);
  k_prepWt<<<(1024*512+255)/256, 256, 0, stream>>>(W_fc1, Wfc1t, 512, 1024, 512);
  k_prepWt<<<(256*1024+255)/256, 256, 0, stream>>>(W_fc2, Wfc2t, 1024, 256, 1024);
  k_cast_bf<<<((N_GRAPHSC*1280)+255)/256, 256, 0, stream>>>(target, tb, N_GRAPHSC*1280);

  // layer-1 attention logits via folded weights (per-node kernels)
  k_wa1<<<(F_INC*20+255)/256, 256, 0, stream>>>(W1, a_src1, a_dst1, Wa1);
  k_att1<<<(N_NODESC+255)/256, 256, 0, stream>>>(x, Wa1, att1);
  k_stats1<<<(N_NODESC+255)/256, 256, 0, stream>>>(att1, rowptr, esrc, stat1);

  // layer-1 (chunked): agg -> zc; FUSED GEMM+elu+projection+att2 -> h2pre,att2
  for (int c = 0; c < C; c++){
    int base = c*R;
    k_agg1<<<R/4, 256, 0, stream>>>(x, att1, stat1, rowptr, esrc, zc, base);
    mfma_fused12<<<(R+63)/64, 256, 0, stream>>>(
        zc, W1t, b1, W2f, h2pre + (size_t)base*OUT2C, att2 + (size_t)base*2,
        a_src2, a_dst2, R);
  }

  // layer-2 softmax stats (den pass emits per-edge exp) + aggregation
  k_stats2<<<(N_NODESC+255)/256, 256, 0, stream>>>(att2, rowptr, esrc, rstat2, ealpha);
  k_agg2<<<(N_NODESC+3)/4, 256, 0, stream>>>(h2pre, ealpha, rstat2, rowptr, esrc,
                                             b2, w_gate, b_gate, h2, wnode);

  // readout (bf16) + MLP head via MFMA (K multiples of 32 -> KVAL=32, no masks)
  k_readout<<<N_GRAPHSC, 128, 0, stream>>>(h2, wnode, batch, xcb);
  mfma_gemm<128,8,1280,32,0,true><<<dim3(N_GRAPHSC/64, 256/128, 1), 256, 0, stream>>>(
      tb, Wxtt, b_xt, xcb + 256, N_GRAPHSC, 256, 1280, 512, 0,0,0,0);
  mfma_gemm<128,8,512,32,1,true><<<dim3(N_GRAPHSC/64, 1024/128, 1), 256, 0, stream>>>(
      xcb, Wfc1t, b_fc1, f1b, N_GRAPHSC, 1024, 512, 1024, 0,0,0,0);
  mfma_gemm<128,8,1024,32,1,true><<<dim3(N_GRAPHSC/64, 256/128, 1), 256, 0, stream>>>(
      f1b, Wfc2t, b_fc2, f2b, N_GRAPHSC, 256, 1024, 256, 0,0,0,0);
  k_final<<<(N_GRAPHSC+3)/4, 256, 0, stream>>>(f2b, W_out, b_out, out);
}

// Round 14
// 616.589 us; speedup vs baseline: 1.0720x; 1.0036x over previous
//
#include <hip/hip_runtime.h>
#include <cstdint>
#include <cstddef>

#define N_NODESC 100000
#define N_EDGESC 400000
#define N_GRAPHSC 2048
#define F_INC 78
#define HEADS1C 10
#define D1C 78           // per-head out dim, layer 1
#define F1C 780          // HEADS1C * D1C
#define OUT2C 128
#define E_TOTC (N_EDGESC + N_NODESC)   // 500000 edges incl. self-loops

typedef unsigned short ushort_t;
typedef __attribute__((ext_vector_type(8))) short short8;
typedef __attribute__((ext_vector_type(4))) float f32x4;
typedef __attribute__((ext_vector_type(4))) unsigned int uint4v;
union U4S8 { uint4v u; short8 s; };

static __device__ __forceinline__ float lrelu(float x){ return x > 0.f ? x : 0.2f*x; }

// fast ELU: v_exp_f32-based (expm1f was ~25 VALU inst; __expf is 2).
static __device__ __forceinline__ float elu_fast(float v){
  return (v > 0.f) ? v : (__expf(v) - 1.0f);
}

// LDS-only barrier: __syncthreads on gfx950 drains vmcnt(0) too, which kills
// in-flight global prefetches.  This waits LDS ops only and leaves global
// loads in flight across the barrier.
static __device__ __forceinline__ void bar_lds(){
  asm volatile("s_waitcnt lgkmcnt(0)" ::: "memory");
  __builtin_amdgcn_s_barrier();
}

// bf16 helpers (round-to-nearest-even)
static __device__ __forceinline__ unsigned short f2bf(float f){
  unsigned int u = __float_as_uint(f);
  unsigned int r = (u + 0x7fffu + ((u >> 16) & 1u)) >> 16;
  return (unsigned short)r;
}
static __device__ __forceinline__ float bf2f(unsigned short h){
  return __uint_as_float(((unsigned int)h) << 16);
}

// ---------------- CSR build ----------------
__global__ void k_deg(const int* __restrict__ ei, int* __restrict__ deg){
  int e = blockIdx.x*256 + threadIdx.x;
  if (e >= E_TOTC) return;
  int dst = (e < N_EDGESC) ? ei[N_EDGESC + e] : (e - N_EDGESC);
  atomicAdd(&deg[dst], 1);
}

__global__ __launch_bounds__(1024) void k_scan1(const int* __restrict__ deg,
                                                int* __restrict__ rowptr,
                                                int* __restrict__ bsum){
  __shared__ int s[1024];
  int t = threadIdx.x, i = blockIdx.x*1024 + t;
  int v = (i < N_NODESC) ? deg[i] : 0;
  s[t] = v; __syncthreads();
  for (int d = 1; d < 1024; d <<= 1){
    int xv = (t >= d) ? s[t-d] : 0;
    __syncthreads();
    s[t] += xv;
    __syncthreads();
  }
  if (i < N_NODESC) rowptr[i+1] = s[t];
  if (t == 1023) bsum[blockIdx.x] = s[t];
}

__global__ void k_scan2(int* __restrict__ bsum, int* __restrict__ rowptr, int nb){
  if (threadIdx.x == 0 && blockIdx.x == 0){
    int run = 0;
    for (int b = 0; b < nb; b++){ int v = bsum[b]; bsum[b] = run; run += v; }
    rowptr[0] = 0;
  }
}

__global__ __launch_bounds__(1024) void k_scan3(int* __restrict__ rowptr,
                                                const int* __restrict__ bsum){
  int i = blockIdx.x*1024 + threadIdx.x;
  if (i < N_NODESC) rowptr[i+1] += bsum[blockIdx.x];
}

__global__ void k_scatter(const int* __restrict__ ei, const int* __restrict__ rowptr,
                          int* __restrict__ cnt, int* __restrict__ esrc){
  int e = blockIdx.x*256 + threadIdx.x;
  if (e >= E_TOTC) return;
  int src, dst;
  if (e < N_EDGESC){ src = ei[e]; dst = ei[N_EDGESC + e]; }
  else { src = dst = e - N_EDGESC; }
  int pos = rowptr[dst] + atomicAdd(&cnt[dst], 1);
  esrc[pos] = src;
}

// ---------------- layer-1 attention logit precompute ----------------
__global__ void k_wa1(const float* __restrict__ W1, const float* __restrict__ a_src1,
                      const float* __restrict__ a_dst1, float* __restrict__ Wa1){
  int i = blockIdx.x*256 + threadIdx.x;
  if (i >= F_INC*2*HEADS1C) return;
  int d = i / (2*HEADS1C), c = i % (2*HEADS1C);
  const float* a = (c < HEADS1C) ? a_src1 : a_dst1;
  int h = (c < HEADS1C) ? c : c - HEADS1C;
  float s = 0.f;
  for (int j = 0; j < D1C; j++) s += W1[d*F1C + h*D1C + j] * a[h*D1C + j];
  Wa1[d*(2*HEADS1C) + c] = s;
}

// one thread per node; acc[20] in regs; x read once via float2.
__global__ __launch_bounds__(256) void k_att1(const float* __restrict__ x,
                                              const float* __restrict__ Wa1,
                                              float* __restrict__ att1){
  int n = blockIdx.x*256 + threadIdx.x;
  if (n >= N_NODESC) return;
  const float* xr = x + (size_t)n*F_INC;
  float acc[20];
  #pragma unroll
  for (int c = 0; c < 20; c++) acc[c] = 0.f;
  for (int d0 = 0; d0 < F_INC; d0 += 2){
    float2 xv = *(const float2*)(xr + d0);
    const float* w0 = Wa1 + d0*20;
    #pragma unroll
    for (int c = 0; c < 20; c++)
      acc[c] += xv.x*w0[c] + xv.y*w0[20 + c];
  }
  float* o = att1 + (size_t)n*20;
  #pragma unroll
  for (int j = 0; j < 10; j++){
    float2 ov; ov.x = acc[2*j]; ov.y = acc[2*j+1];
    *(float2*)(o + 2*j) = ov;
  }
}

// one thread per node, all 10 heads; den pass also emits the UNSCALED
// per-(edge,head) exp values to ealpha1[p*10+h] (computed anyway — k_agg1
// rescales by rd, giving the identical float product it used to compute).
__global__ __launch_bounds__(256) void k_stats1(const float* __restrict__ att1,
                                                const int* __restrict__ rowptr,
                                                const int* __restrict__ esrc,
                                                float* __restrict__ stat1,
                                                float* __restrict__ ealpha1){
  int n = blockIdx.x*256 + threadIdx.x;
  if (n >= N_NODESC) return;
  float ad[10];
  {
    const float* a = att1 + (size_t)n*20 + 10;
    #pragma unroll
    for (int j = 0; j < 5; j++){
      float2 v = *(const float2*)(a + 2*j);
      ad[2*j] = v.x; ad[2*j+1] = v.y;
    }
  }
  int b = rowptr[n], e = rowptr[n+1];
  float m[10];
  #pragma unroll
  for (int h = 0; h < 10; h++) m[h] = -1e30f;
  for (int p = b; p < e; p += 2){
    int s0 = esrc[p];
    int s1 = esrc[(p+1 < e) ? p+1 : p];
    float2 v0[5], v1[5];
    #pragma unroll
    for (int j = 0; j < 5; j++) v0[j] = *(const float2*)(att1 + (size_t)s0*20 + 2*j);
    #pragma unroll
    for (int j = 0; j < 5; j++) v1[j] = *(const float2*)(att1 + (size_t)s1*20 + 2*j);
    #pragma unroll
    for (int h = 0; h < 10; h++){
      float a0 = (h & 1) ? v0[h>>1].y : v0[h>>1].x;
      m[h] = fmaxf(m[h], lrelu(a0 + ad[h]));
    }
    if (p+1 < e){
      #pragma unroll
      for (int h = 0; h < 10; h++){
        float a1 = (h & 1) ? v1[h>>1].y : v1[h>>1].x;
        m[h] = fmaxf(m[h], lrelu(a1 + ad[h]));
      }
    }
  }
  float den[10];
  #pragma unroll
  for (int h = 0; h < 10; h++) den[h] = 0.f;
  for (int p = b; p < e; p += 2){
    int s0 = esrc[p];
    int s1 = esrc[(p+1 < e) ? p+1 : p];
    float2 v0[5], v1[5];
    #pragma unroll
    for (int j = 0; j < 5; j++) v0[j] = *(const float2*)(att1 + (size_t)s0*20 + 2*j);
    #pragma unroll
    for (int j = 0; j < 5; j++) v1[j] = *(const float2*)(att1 + (size_t)s1*20 + 2*j);
    float* e0 = ealpha1 + (size_t)p*10;
    #pragma unroll
    for (int h = 0; h < 10; h++){
      float a0 = (h & 1) ? v0[h>>1].y : v0[h>>1].x;
      float ev = expf(lrelu(a0 + ad[h]) - m[h]);
      den[h] += ev;
      e0[h] = ev;
    }
    if (p+1 < e){
      float* e1 = ealpha1 + (size_t)(p+1)*10;
      #pragma unroll
      for (int h = 0; h < 10; h++){
        float a1 = (h & 1) ? v1[h>>1].y : v1[h>>1].x;
        float ev = expf(lrelu(a1 + ad[h]) - m[h]);
        den[h] += ev;
        e1[h] = ev;
      }
    }
  }
  float* o = stat1 + (size_t)n*20;
  #pragma unroll
  for (int h = 0; h < 10; h++){
    o[h] = m[h];
    o[10 + h] = 1.f/(den[h] + 1e-16f);
  }
}

// LDS-free aggregation (v14): lane = feature d; coalesced x gathers; alpha
// loaded PRECOMPUTED from ealpha1 (contiguous per edge) * rd — the scattered
// att1 gathers + expf chains are gone.  shfl broadcast + FMA loop unchanged.
// ev*rd is the same float product v9 computed -> results identical.
__global__ __launch_bounds__(256) void k_agg1(
    const float* __restrict__ x, const float* __restrict__ ealpha1,
    const float* __restrict__ stat1, const int* __restrict__ rowptr,
    const int* __restrict__ esrc, ushort_t* __restrict__ zc, int base){
  int wv = threadIdx.x >> 6;
  int l  = threadIdx.x & 63;
  int nl = blockIdx.x*4 + wv;          // chunk-local node index (grid = R/4)
  int n  = base + nl;
  int b = rowptr[n], e = rowptr[n+1];
  float rd = 0.f;
  if (l < HEADS1C) rd = stat1[n*20 + 10 + l];
  float acc0[10], acc1[10];
  #pragma unroll
  for (int h = 0; h < 10; h++){ acc0[h] = 0.f; acc1[h] = 0.f; }
  bool lo14 = (l < 14);
  for (int p = b; p < e; p += 4){
    int c = e - p; if (c > 4) c = 4;
    int ss[4];
    #pragma unroll
    for (int j = 0; j < 4; j++) ss[j] = esrc[p + (j < c ? j : 0)];
    float alv[4];
    #pragma unroll
    for (int j = 0; j < 4; j++){
      float ev = (l < HEADS1C) ? ealpha1[(size_t)(p + (j < c ? j : 0))*10 + l] : 0.f;
      alv[j] = (j < c) ? ev * rd : 0.f;
    }
    float xv0[4], xv1[4];
    #pragma unroll
    for (int j = 0; j < 4; j++){
      const float* xr = x + (size_t)ss[j]*F_INC;
      xv0[j] = xr[l];
      xv1[j] = lo14 ? xr[64 + l] : 0.f;
    }
    #pragma unroll
    for (int h = 0; h < 10; h++){
      float a0 = __shfl(alv[0], h);
      float a1 = __shfl(alv[1], h);
      float a2 = __shfl(alv[2], h);
      float a3 = __shfl(alv[3], h);
      float s0 = a0*xv0[0] + a1*xv0[1] + a2*xv0[2] + a3*xv0[3];
      float s1 = a0*xv1[0] + a1*xv1[1] + a2*xv1[2] + a3*xv1[3];
      acc0[h] += s0;
      acc1[h] += s1;
    }
  }
  ushort_t* zr = zc + (size_t)nl*F1C;
  #pragma unroll
  for (int h = 0; h < 10; h++){
    zr[h*78 + l] = f2bf(acc0[h]);
    if (lo14) zr[h*78 + 64 + l] = f2bf(acc1[h]);
  }
}

// ---------------- weight pre-transpose (zero-padded bf16) ----------------
__global__ void k_prepW1(const float* __restrict__ W1, ushort_t* __restrict__ W1t){
  // W1t[h][n(80)][k(96)] = bf16(W1[k][h*78+n]) with zero pad
  int i = blockIdx.x*256 + threadIdx.x;
  if (i >= HEADS1C*80*96) return;
  int h = i / (80*96), rem = i % (80*96), n = rem / 96, k = rem % 96;
  float v = (n < D1C && k < F_INC) ? W1[(size_t)k*F1C + h*D1C + n] : 0.f;
  W1t[i] = f2bf(v);
}

// W2f[h][n(128)][k(96)] = bf16(W2[h*78+k][n]) with zero pad in k (78..95)
__global__ void k_prepW2f(const float* __restrict__ W2, ushort_t* __restrict__ W2f){
  int i = blockIdx.x*256 + threadIdx.x;
  if (i >= HEADS1C*128*96) return;
  int h = i / (128*96), rem = i % (128*96), n = rem / 96, k = rem % 96;
  float v = (k < D1C) ? W2[(size_t)(h*D1C + k)*OUT2C + n] : 0.f;
  W2f[i] = f2bf(v);
}

// generic: Wt[n][k(KB)] = bf16(W[k][n]) zero-padded in k
__global__ void k_prepWt(const float* __restrict__ W, ushort_t* __restrict__ Wt,
                         int Kdim, int Ndim, int KB){
  int i = blockIdx.x*256 + threadIdx.x;
  if (i >= Ndim*KB) return;
  int n = i / KB, k = i % KB;
  float v = (k < Kdim) ? W[(size_t)k*Ndim + n] : 0.f;
  Wt[i] = f2bf(v);
}

__global__ void k_cast_bf(const float* __restrict__ in, ushort_t* __restrict__ o, int n){
  int i = blockIdx.x*256 + threadIdx.x;
  if (i < n) o[i] = f2bf(in[i]);
}

// ---------------- MFMA bf16 GEMM: C[M,N] = act(A @ Bt^T + bias), bf16 out ---
template<int BN, int NT, int KB, int KVAL, int ACT, bool HASBIAS>
__global__ __launch_bounds__(256) void mfma_gemm(
    const ushort_t* __restrict__ A, const ushort_t* __restrict__ Bt,
    const float* __restrict__ bias, ushort_t* __restrict__ C,
    int M, int N, int lda, int ldc,
    int zsA, int zsBt, int zsC, int zsBias)
{
  __shared__ unsigned int As[64][20];   // 64 rows x 32 bf16 (+pad)
  __shared__ unsigned int Bs[BN][20];
  int z = blockIdx.z;
  A += (size_t)z*zsA; Bt += (size_t)z*zsBt; C += (size_t)z*zsC;
  const float* bz = HASBIAS ? (bias + (size_t)z*zsBias) : nullptr;
  int m0 = blockIdx.x*64;
  int n0 = blockIdx.y*BN;
  int t = threadIdx.x;
  int w = t >> 6, lane = t & 63;
  int q = lane >> 4, li = lane & 15;
  f32x4 acc[NT];
  #pragma unroll
  for (int i = 0; i < NT; i++) acc[i] = (f32x4){0.f,0.f,0.f,0.f};

  int am = t >> 2;           // staged row 0..63
  int ak0 = (t & 3)*8;       // short col base 0,8,16,24
  int gm = m0 + am;
  bool rv = (gm < M);

  #pragma unroll
  for (int ki = 0; ki < KB/32; ki++){
    const int kt = ki*32;
    int nv;
    if (ki == KB/32 - 1){
      int d = KVAL - ak0; nv = d < 0 ? 0 : (d > 8 ? 8 : d);
    } else nv = 8;
    {
      unsigned u0=0u, u1=0u, u2=0u, u3=0u;
      if (rv && nv > 0){
        const unsigned int* ap = (const unsigned int*)(A + (size_t)gm*lda + kt + ak0);
        u0 = ap[0]; u1 = ap[1]; u2 = ap[2]; u3 = ap[3];
        int ndw = nv >> 1;
        if (ndw < 4) u3 = 0u;
        if (ndw < 3) u2 = 0u;
        if (ndw < 2) u1 = 0u;
      }
      int c0 = (t & 3)*4;
      As[am][c0] = u0; As[am][c0+1] = u1; As[am][c0+2] = u2; As[am][c0+3] = u3;
    }
    for (int g = t; g < BN*4; g += 256){
      int n = g >> 2, c0 = (g & 3)*4;
      const unsigned int* bp = (const unsigned int*)(Bt + (size_t)(n0 + n)*KB + kt + c0*2);
      Bs[n][c0] = bp[0]; Bs[n][c0+1] = bp[1]; Bs[n][c0+2] = bp[2]; Bs[n][c0+3] = bp[3];
    }
    __syncthreads();
    U4S8 a; a.u = *(const uint4v*)&As[w*16 + li][q*4];
    #pragma unroll
    for (int nt = 0; nt < NT; nt++){
      U4S8 b; b.u = *(const uint4v*)&Bs[nt*16 + li][q*4];
      acc[nt] = __builtin_amdgcn_mfma_f32_16x16x32_bf16(a.s, b.s, acc[nt], 0, 0, 0);
    }
    __syncthreads();
  }
  #pragma unroll
  for (int nt = 0; nt < NT; nt++){
    int col = n0 + nt*16 + li;
    if (col >= N) continue;
    float bv = HASBIAS ? bz[col] : 0.f;
    #pragma unroll
    for (int r = 0; r < 4; r++){
      int gmr = m0 + w*16 + q*4 + r;
      if (gmr >= M) continue;
      float v = acc[nt][r] + bv;
      if (ACT == 1) v = fmaxf(v, 0.f);
      else if (ACT == 2) v = (v > 0.f) ? v : (__expf(v) - 1.0f);
      C[(size_t)gmr*ldc + col] = f2bf(v);
    }
  }
}

// ---------------- FUSED layer-1 GEMM + projection (v11 structure) ----------
// h2pre[m, 0:128] = sum_h  elu( zc[m, h*78:+78] @ W1h + b1_h )  @  W2[h*78:+78, 0:128]
// + fused att2 logits from the bf16-rounded h2pre values.
// Split weight buffers Bs1/Bs2 (flat stride 48), 2 bar_lds/head, T14 reg
// staging, one-head-ahead A prefetch, (256,3) reg cap.
__global__ __launch_bounds__(256, 3) void mfma_fused12(
    const ushort_t* __restrict__ zc, const ushort_t* __restrict__ W1t,
    const float* __restrict__ b1, const ushort_t* __restrict__ W2f,
    ushort_t* __restrict__ h2pre, float* __restrict__ att2,
    const float* __restrict__ a_src2, const float* __restrict__ a_dst2,
    int M)
{
  __shared__ unsigned int Bs1[80*48];   // W1t[h] flat: 80 rows x 48 dw
  __shared__ unsigned int Bs2[128*48];  // W2f[h] flat: 128 rows x 48 dw
  __shared__ unsigned int Ts[64][52];   // T bf16 (96 shorts + pad), wave-private rows
  int m0 = blockIdx.x*64;
  int t = threadIdx.x;
  int w = t >> 6, lane = t & 63;
  int q = lane >> 4, li = lane & 15;

  const uint4v* w1v = (const uint4v*)W1t;   // [h*960 + g] 16B groups
  const uint4v* w2v = (const uint4v*)W2f;   // [h*1536 + g]

  // ---- staging-register helpers (T14 split: issue early, ds_write late) ----
  uint4v rw1[4], rw2[6];
  auto issueW1 = [&](int h){
    #pragma unroll
    for (int g0 = 0; g0 < 4; g0++){
      int g = t + g0*256;
      if (g < 960) rw1[g0] = w1v[(size_t)h*960 + g];
    }
  };
  auto writeW1 = [&](){
    #pragma unroll
    for (int g0 = 0; g0 < 4; g0++){
      int g = t + g0*256;
      if (g < 960) *(uint4v*)&Bs1[g*4] = rw1[g0];
    }
  };
  auto issueW2 = [&](int h){
    #pragma unroll
    for (int g0 = 0; g0 < 6; g0++)
      rw2[g0] = w2v[(size_t)h*1536 + t + g0*256];
  };
  auto writeW2 = [&](){
    #pragma unroll
    for (int g0 = 0; g0 < 6; g0++){
      int g = t + g0*256;
      *(uint4v*)&Bs2[g*4] = rw2[g0];
    }
  };

  f32x4 acc2[8];
  #pragma unroll
  for (int i = 0; i < 8; i++) acc2[i] = (f32x4){0.f,0.f,0.f,0.f};

  issueW1(0);                           // both head-0 weight tiles in flight
  issueW2(0);

  // zero Ts pad dwords 39..47 (cols 78..95) once (read in stage-2 ki=2;
  // published by the prologue barrier)
  for (int i = t; i < 64*9; i += 256) Ts[i/9][39 + i%9] = 0u;

  // this lane's A row: m0 + w*16 + li; k-chunk q (shorts q*8..q*8+7 per 32-k tile)
  int ar = m0 + w*16 + li;
  bool rv = (ar < M);
  const unsigned int* abase = (const unsigned int*)(zc + (size_t)ar*F1C);

  // A-fragment loader for head h: af[ki], k = ki*32 + q*8 (head slice is 78 wide)
  auto lda = [&](int h, uint4v* af){
    af[0] = (uint4v){0u,0u,0u,0u};
    af[1] = (uint4v){0u,0u,0u,0u};
    af[2] = (uint4v){0u,0u,0u,0u};
    if (rv){
      const unsigned int* p = abase + h*39 + q*4;    // h*78 shorts = h*39 dwords
      af[0][0]=p[0];  af[0][1]=p[1];  af[0][2]=p[2];  af[0][3]=p[3];
      af[1][0]=p[16]; af[1][1]=p[17]; af[1][2]=p[18]; af[1][3]=p[19];
      if (q < 2){                                    // k 64..79 only (78,79 zeroed)
        af[2][0]=p[32]; af[2][1]=p[33]; af[2][2]=p[34]; af[2][3]=p[35];
        if (q == 1) af[2][3] = 0u;
      }
    }
  };

  uint4v acur[3], anxt[3];
  lda(0, acur);

  writeW1();                            // Bs1 <- W1[0] (vmcnt wait, once)
  bar_lds();                            // Bs1 + Ts-pad visible

  #pragma unroll 1
  for (int h = 0; h < HEADS1C; h++){
    int hn = (h+1 < HEADS1C) ? h+1 : 0;
    writeW2();                          // Bs2 <- W2[h]; rw2 dies (stage-1 reads Bs1)
    issueW1(hn);                        // W1[h+1] -> regs, in flight over stage-1
    // per-head bias: 5 per lane (cols nt*16+li)
    float bv[5];
    #pragma unroll
    for (int nt = 0; nt < 5; nt++){
      int col = nt*16 + li;
      bv[nt] = (col < D1C) ? b1[h*D1C + col] : 0.f;
    }

    // stage-1 MFMA: T(64x80) = zc_h @ W1h (A from registers, B from Bs1)
    f32x4 acc1[5];
    #pragma unroll
    for (int i = 0; i < 5; i++) acc1[i] = (f32x4){0.f,0.f,0.f,0.f};
    #pragma unroll
    for (int ki = 0; ki < 3; ki++){
      U4S8 a; a.u = acur[ki];
      #pragma unroll
      for (int nt = 0; nt < 5; nt++){
        U4S8 b; b.u = *(const uint4v*)&Bs1[(nt*16 + li)*48 + ki*16 + q*4];
        acc1[nt] = __builtin_amdgcn_mfma_f32_16x16x32_bf16(a.s, b.s, acc1[nt], 0, 0, 0);
      }
    }
    // bias + fast elu -> bf16 into Ts (wave-private rows)
    #pragma unroll
    for (int nt = 0; nt < 5; nt++){
      int col = nt*16 + li;
      #pragma unroll
      for (int r = 0; r < 4; r++){
        int row = w*16 + q*4 + r;
        float v = elu_fast(acc1[nt][r] + bv[nt]);
        ((ushort_t*)&Ts[row][0])[col] = f2bf(v);
      }
    }
    // prefetch next head's A frags (zc, L3) — stays in flight across barriers
    lda(hn, anxt);

    bar_lds();                          // stage-1 Bs1 reads done; Bs2+Ts visible
    writeW1();                          // Bs1 <- W1[h+1]; rw1 dies (stage-2 reads Bs2)
    issueW2(hn);                        // W2[h+1] -> regs, in flight over stage-2

    // stage-2 MFMA: acc2 += T @ W2f[h] (A from own Ts rows, B from Bs2)
    #pragma unroll
    for (int ki = 0; ki < 3; ki++){
      U4S8 a; a.u = *(const uint4v*)&Ts[w*16 + li][ki*16 + q*4];
      #pragma unroll
      for (int nt = 0; nt < 8; nt++){
        U4S8 b; b.u = *(const uint4v*)&Bs2[(nt*16 + li)*48 + ki*16 + q*4];
        acc2[nt] = __builtin_amdgcn_mfma_f32_16x16x32_bf16(a.s, b.s, acc2[nt], 0, 0, 0);
      }
    }
    bar_lds();                          // stage-2 Bs2 reads done; Bs1 writes visible
    acur[0] = anxt[0]; acur[1] = anxt[1]; acur[2] = anxt[2];
  }

  // ---- epilogue: h2pre bf16 + fused att2 logits (from bf16-rounded vals) ---
  float as2[8], ad2[8];
  #pragma unroll
  for (int nt = 0; nt < 8; nt++){
    int col = nt*16 + li;
    as2[nt] = a_src2[col];
    ad2[nt] = a_dst2[col];
  }
  #pragma unroll
  for (int r = 0; r < 4; r++){
    int gmr = m0 + w*16 + q*4 + r;
    float p0 = 0.f, p1 = 0.f;
    ushort_t hv[8];
    #pragma unroll
    for (int nt = 0; nt < 8; nt++){
      ushort_t hb = f2bf(acc2[nt][r]);
      float vb = bf2f(hb);
      p0 += vb*as2[nt]; p1 += vb*ad2[nt];
      hv[nt] = hb;
    }
    #pragma unroll
    for (int off = 1; off < 16; off <<= 1){
      p0 += __shfl_xor(p0, off);
      p1 += __shfl_xor(p1, off);
    }
    if (gmr < M){
      #pragma unroll
      for (int nt = 0; nt < 8; nt++)
        h2pre[(size_t)gmr*OUT2C + nt*16 + li] = hv[nt];
      if (li == 0){
        att2[(size_t)gmr*2]     = p0;
        att2[(size_t)gmr*2 + 1] = p1;
      }
    }
  }
}

// per node: max + 1/(sum exp); the den pass writes the UNSCALED per-edge
// exp values inline (they are computed anyway) — k_agg2 scales by rd.
__global__ void k_stats2(const float* __restrict__ att2, const int* __restrict__ rowptr,
                         const int* __restrict__ esrc, float* __restrict__ rstat2,
                         float* __restrict__ ealpha){
  int n = blockIdx.x*256 + threadIdx.x;
  if (n >= N_NODESC) return;
  float ad = att2[n*2+1];
  int b = rowptr[n], e = rowptr[n+1];
  float m = -1e30f;
  for (int p = b; p < e; p += 4){
    int c = e - p; if (c > 4) c = 4;
    float v[4];
    #pragma unroll
    for (int j = 0; j < 4; j++){ int s = esrc[p + (j < c ? j : 0)]; v[j] = att2[s*2]; }
    #pragma unroll
    for (int j = 0; j < 4; j++) if (j < c) m = fmaxf(m, lrelu(v[j] + ad));
  }
  float den = 0.f;
  for (int p = b; p < e; p += 4){
    int c = e - p; if (c > 4) c = 4;
    float v[4];
    #pragma unroll
    for (int j = 0; j < 4; j++){ int s = esrc[p + (j < c ? j : 0)]; v[j] = att2[s*2]; }
    #pragma unroll
    for (int j = 0; j < 4; j++){
      if (j < c){
        float ev = expf(lrelu(v[j] + ad) - m);
        den += ev;
        ealpha[p + j] = ev;
      }
    }
  }
  rstat2[n] = 1.f/(den + 1e-16f);
}

// wave per node; per-edge exp loaded precomputed (wave-uniform ->
// scalarizable), scaled by the node's rd; inner loop is pure gather + FMA.
__global__ void k_agg2(const ushort_t* __restrict__ h2pre,
                       const float* __restrict__ ealpha,
                       const float* __restrict__ rstat2,
                       const int* __restrict__ rowptr,
                       const int* __restrict__ esrc, const float* __restrict__ b2,
                       const float* __restrict__ w_gate, const float* __restrict__ b_gate,
                       float* __restrict__ h2, float* __restrict__ wnode){
  int n = blockIdx.x*4 + (threadIdx.x >> 6);
  int l = threadIdx.x & 63;
  if (n >= N_NODESC) return;
  float rd = rstat2[n];
  int b = rowptr[n], e = rowptr[n+1];
  float a0 = 0.f, a1 = 0.f;
  for (int p = b; p < e; p += 4){
    int c = e - p; if (c > 4) c = 4;
    int ss[4]; float al[4];
    #pragma unroll
    for (int j = 0; j < 4; j++) ss[j] = esrc[p + (j < c ? j : 0)];
    #pragma unroll
    for (int j = 0; j < 4; j++) al[j] = (j < c) ? ealpha[p + j] * rd : 0.f;
    unsigned u[4];
    #pragma unroll
    for (int j = 0; j < 4; j++) u[j] = *(const unsigned*)(h2pre + (size_t)ss[j]*OUT2C + 2*l);
    #pragma unroll
    for (int j = 0; j < 4; j++){
      a0 += al[j] * bf2f((ushort_t)(u[j] & 0xffffu));
      a1 += al[j] * bf2f((ushort_t)(u[j] >> 16));
    }
  }
  float v0 = fmaxf(a0 + b2[2*l],   0.f);
  float v1 = fmaxf(a1 + b2[2*l+1], 0.f);
  float2 hv; hv.x = v0; hv.y = v1;
  *(float2*)(h2 + (size_t)n*OUT2C + 2*l) = hv;
  float pp = v0*w_gate[2*l] + v1*w_gate[2*l+1];
  #pragma unroll
  for (int off = 32; off; off >>= 1) pp += __shfl_xor(pp, off);
  if (l == 0) wnode[n] = 1.f/(1.f + expf(-(pp + b_gate[0])));
}

// one block per graph: weighted-sum + max readout, bf16 out into xcb[:, 0:256]
__global__ __launch_bounds__(128) void k_readout(const float* __restrict__ h2,
                                                 const float* __restrict__ wnode,
                                                 const int* __restrict__ batch,
                                                 ushort_t* __restrict__ xcb){
  __shared__ int lohi[2];
  int g = blockIdx.x, t = threadIdx.x;
  if (t == 0){
    int lo = 0, hi = N_NODESC;
    while (lo < hi){ int mid = (lo+hi) >> 1; if (batch[mid] < g) lo = mid+1; else hi = mid; }
    lohi[0] = lo;
    int lo2 = lo; hi = N_NODESC;
    while (lo2 < hi){ int mid = (lo2+hi) >> 1; if (batch[mid] < g+1) lo2 = mid+1; else hi = mid; }
    lohi[1] = lo2;
  }
  __syncthreads();
  int lo = lohi[0], hi = lohi[1];
  float sum = 0.f, mx = 0.f;
  for (int n = lo; n < hi; n++){
    float v = h2[(size_t)n*OUT2C + t];
    sum += v * wnode[n];
    mx = fmaxf(mx, v);
  }
  xcb[(size_t)g*512 + t] = f2bf(sum);
  xcb[(size_t)g*512 + 128 + t] = f2bf(mx);
}

__global__ void k_final(const ushort_t* __restrict__ f2b, const float* __restrict__ W_out,
                        const float* __restrict__ b_out, float* __restrict__ out){
  int g = blockIdx.x*4 + (threadIdx.x >> 6);
  int l = threadIdx.x & 63;
  if (g >= N_GRAPHSC) return;
  float s = 0.f;
  #pragma unroll
  for (int k = 0; k < 4; k++) s += bf2f(f2b[(size_t)g*256 + l + 64*k]) * W_out[l + 64*k];
  #pragma unroll
  for (int off = 32; off; off >>= 1) s += __shfl_xor(s, off);
  if (l == 0) out[g] = s + b_out[0];
}

extern "C" void kernel_launch(void* const* d_in, const int* in_sizes, int n_in,
                              void* d_out, int out_size, void* d_ws, size_t ws_size,
                              hipStream_t stream) {
  const float* x      = (const float*)d_in[0];
  const int*   ei     = (const int*)d_in[1];
  const int*   batch  = (const int*)d_in[2];
  const float* target = (const float*)d_in[3];
  const float* W1     = (const float*)d_in[4];
  const float* a_src1 = (const float*)d_in[5];
  const float* a_dst1 = (const float*)d_in[6];
  const float* b1     = (const float*)d_in[7];
  const float* W2     = (const float*)d_in[8];
  const float* a_src2 = (const float*)d_in[9];
  const float* a_dst2 = (const float*)d_in[10];
  const float* b2     = (const float*)d_in[11];
  const float* w_gate = (const float*)d_in[12];
  const float* b_gate = (const float*)d_in[13];
  const float* W_xt   = (const float*)d_in[14];
  const float* b_xt   = (const float*)d_in[15];
  const float* W_fc1  = (const float*)d_in[16];
  const float* b_fc1  = (const float*)d_in[17];
  const float* W_fc2  = (const float*)d_in[18];
  const float* b_fc2  = (const float*)d_in[19];
  const float* W_out  = (const float*)d_in[20];
  const float* b_out  = (const float*)d_in[21];
  float* out = (float*)d_out;

  // ---- adaptive chunking (C=1 when workspace allows; ealpha1 adds 20MB,
  // C=2 threshold raised accordingly) ----
  const size_t MB = (size_t)1 << 20;
  int C;
  if      (ws_size >= 245*MB) C = 1;
  else if (ws_size >= 170*MB) C = 2;
  else                        C = 4;
  const int R = N_NODESC / C;          // R and R/4 integral for C in {1,2,4}

  char* p = (char*)d_ws;
  auto carve = [&](size_t bytes) -> char* {
    char* r = p; p += (bytes + 255) & ~(size_t)255; return r;
  };
  int*   deg    = (int*)  carve((size_t)N_NODESC*4);
  int*   rowptr = (int*)  carve((size_t)(N_NODESC+1)*4);
  int*   cnt    = (int*)  carve((size_t)N_NODESC*4);
  int*   esrc   = (int*)  carve((size_t)E_TOTC*4);
  int*   bsum   = (int*)  carve(128*4);
  float* Wa1    = (float*)carve((size_t)F_INC*20*4);
  float* att1   = (float*)carve((size_t)N_NODESC*20*4);
  float* stat1  = (float*)carve((size_t)N_NODESC*20*4);
  float* ealpha1= (float*)carve((size_t)E_TOTC*10*4);   // per-(edge,head) exp
  float* att2   = (float*)carve((size_t)N_NODESC*2*4);
  float* rstat2 = (float*)carve((size_t)N_NODESC*4);
  float* ealpha = (float*)carve((size_t)E_TOTC*4);
  float* wnode  = (float*)carve((size_t)N_NODESC*4);
  ushort_t* W1t   = (ushort_t*)carve((size_t)HEADS1C*80*96*2);
  ushort_t* W2f   = (ushort_t*)carve((size_t)HEADS1C*128*96*2);
  ushort_t* Wxtt  = (ushort_t*)carve((size_t)256*1280*2);
  ushort_t* Wfc1t = (ushort_t*)carve((size_t)1024*512*2);
  ushort_t* Wfc2t = (ushort_t*)carve((size_t)256*1024*2);
  ushort_t* tb    = (ushort_t*)carve((size_t)N_GRAPHSC*1280*2);
  ushort_t* h2pre = (ushort_t*)carve((size_t)N_NODESC*OUT2C*2);
  ushort_t* xcb   = (ushort_t*)carve((size_t)N_GRAPHSC*512*2);
  ushort_t* f1b   = (ushort_t*)carve((size_t)N_GRAPHSC*1024*2);
  ushort_t* f2b   = (ushort_t*)carve((size_t)N_GRAPHSC*256*2);
  size_t big_bytes = (size_t)R*F1C*2 + 4096;            // zc (bf16) + overread slack
  size_t h2_bytes  = (size_t)N_NODESC*OUT2C*4;          // h2 (fp32)
  char*  BIG = carve(big_bytes > h2_bytes ? big_bytes : h2_bytes);
  ushort_t* zc  = (ushort_t*)BIG;
  float* h2 = (float*)BIG;   // overlays zc AFTER the fused layer-1/2 pass is done

  hipMemsetAsync(deg, 0, (size_t)N_NODESC*4, stream);
  hipMemsetAsync(cnt, 0, (size_t)N_NODESC*4, stream);

  // CSR by destination (self-loops appended)
  k_deg<<<(E_TOTC+255)/256, 256, 0, stream>>>(ei, deg);
  int nb = (N_NODESC + 1023)/1024;
  k_scan1<<<nb, 1024, 0, stream>>>(deg, rowptr, bsum);
  k_scan2<<<1, 64, 0, stream>>>(bsum, rowptr, nb);
  k_scan3<<<nb, 1024, 0, stream>>>(rowptr, bsum);
  k_scatter<<<(E_TOTC+255)/256, 256, 0, stream>>>(ei, rowptr, cnt, esrc);

  // weight prep (bf16 transposed, zero-padded) + target cast
  k_prepW1<<<(HEADS1C*80*96+255)/256, 256, 0, stream>>>(W1, W1t);
  k_prepW2f<<<(HEADS1C*128*96+255)/256, 256, 0, stream>>>(W2, W2f);
  k_prepWt<<<(256*1280+255)/256, 256, 0, stream>>>(W_xt, Wxtt, 1280, 256, 1280);
  k_prepWt<<<(1024*512+255)/256, 256, 0, stream>>>(W_fc1, Wfc1t, 512, 1024, 512);
  k_prepWt<<<(256*1024+255)/256, 256, 0, stream>>>(W_fc2, Wfc2t, 1024, 256, 1024);
  k_cast_bf<<<((N_GRAPHSC*1280)+255)/256, 256, 0, stream>>>(target, tb, N_GRAPHSC*1280);

  // layer-1 attention logits via folded weights (per-node kernels)
  k_wa1<<<(F_INC*20+255)/256, 256, 0, stream>>>(W1, a_src1, a_dst1, Wa1);
  k_att1<<<(N_NODESC+255)/256, 256, 0, stream>>>(x, Wa1, att1);
  k_stats1<<<(N_NODESC+255)/256, 256, 0, stream>>>(att1, rowptr, esrc, stat1, ealpha1);

  // layer-1 (chunked): agg -> zc; FUSED GEMM+elu+projection+att2 -> h2pre,att2
  for (int c = 0; c < C; c++){
    int base = c*R;
    k_agg1<<<R/4, 256, 0, stream>>>(x, ealpha1, stat1, rowptr, esrc, zc, base);
    mfma_fused12<<<(R+63)/64, 256, 0, stream>>>(
        zc, W1t, b1, W2f, h2pre + (size_t)base*OUT2C, att2 + (size_t)base*2,
        a_src2, a_dst2, R);
  }

  // layer-2 softmax stats (den pass emits per-edge exp) + aggregation
  k_stats2<<<(N_NODESC+255)/256, 256, 0, stream>>>(att2, rowptr, esrc, rstat2, ealpha);
  k_agg2<<<(N_NODESC+3)/4, 256, 0, stream>>>(h2pre, ealpha, rstat2, rowptr, esrc,
                                             b2, w_gate, b_gate, h2, wnode);

  // readout (bf16) + MLP head via MFMA (K multiples of 32 -> KVAL=32, no masks)
  k_readout<<<N_GRAPHSC, 128, 0, stream>>>(h2, wnode, batch, xcb);
  mfma_gemm<128,8,1280,32,0,true><<<dim3(N_GRAPHSC/64, 256/128, 1), 256, 0, stream>>>(
      tb, Wxtt, b_xt, xcb + 256, N_GRAPHSC, 256, 1280, 512, 0,0,0,0);
  mfma_gemm<128,8,512,32,1,true><<<dim3(N_GRAPHSC/64, 1024/128, 1), 256, 0, stream>>>(
      xcb, Wfc1t, b_fc1, f1b, N_GRAPHSC, 1024, 512, 1024, 0,0,0,0);
  mfma_gemm<128,8,1024,32,1,true><<<dim3(N_GRAPHSC/64, 256/128, 1), 256, 0, stream>>>(
      f1b, Wfc2t, b_fc2, f2b, N_GRAPHSC, 256, 1024, 256, 0,0,0,0);
  k_final<<<(N_GRAPHSC+3)/4, 256, 0, stream>>>(f2b, W_out, b_out, out);
}

// Round 15
// 608.138 us; speedup vs baseline: 1.0869x; 1.0139x over previous
//
#include <hip/hip_runtime.h>
#include <cstdint>
#include <cstddef>

#define N_NODESC 100000
#define N_EDGESC 400000
#define N_GRAPHSC 2048
#define F_INC 78
#define HEADS1C 10
#define D1C 78           // per-head out dim, layer 1
#define F1C 780          // HEADS1C * D1C
#define OUT2C 128
#define E_TOTC (N_EDGESC + N_NODESC)   // 500000 edges incl. self-loops

typedef unsigned short ushort_t;
typedef __attribute__((ext_vector_type(8))) short short8;
typedef __attribute__((ext_vector_type(4))) float f32x4;
typedef __attribute__((ext_vector_type(4))) unsigned int uint4v;
union U4S8 { uint4v u; short8 s; };

static __device__ __forceinline__ float lrelu(float x){ return x > 0.f ? x : 0.2f*x; }

// fast ELU: v_exp_f32-based (expm1f was ~25 VALU inst; __expf is 2).
static __device__ __forceinline__ float elu_fast(float v){
  return (v > 0.f) ? v : (__expf(v) - 1.0f);
}

// LDS-only barrier: __syncthreads on gfx950 drains vmcnt(0) too, which kills
// in-flight global prefetches.  This waits LDS ops only and leaves global
// loads in flight across the barrier.
static __device__ __forceinline__ void bar_lds(){
  asm volatile("s_waitcnt lgkmcnt(0)" ::: "memory");
  __builtin_amdgcn_s_barrier();
}

// bf16 helpers (round-to-nearest-even)
static __device__ __forceinline__ unsigned short f2bf(float f){
  unsigned int u = __float_as_uint(f);
  unsigned int r = (u + 0x7fffu + ((u >> 16) & 1u)) >> 16;
  return (unsigned short)r;
}
static __device__ __forceinline__ float bf2f(unsigned short h){
  return __uint_as_float(((unsigned int)h) << 16);
}

// ---------------- CSR build ----------------
__global__ void k_deg(const int* __restrict__ ei, int* __restrict__ deg){
  int e = blockIdx.x*256 + threadIdx.x;
  if (e >= E_TOTC) return;
  int dst = (e < N_EDGESC) ? ei[N_EDGESC + e] : (e - N_EDGESC);
  atomicAdd(&deg[dst], 1);
}

__global__ __launch_bounds__(1024) void k_scan1(const int* __restrict__ deg,
                                                int* __restrict__ rowptr,
                                                int* __restrict__ bsum){
  __shared__ int s[1024];
  int t = threadIdx.x, i = blockIdx.x*1024 + t;
  int v = (i < N_NODESC) ? deg[i] : 0;
  s[t] = v; __syncthreads();
  for (int d = 1; d < 1024; d <<= 1){
    int xv = (t >= d) ? s[t-d] : 0;
    __syncthreads();
    s[t] += xv;
    __syncthreads();
  }
  if (i < N_NODESC) rowptr[i+1] = s[t];
  if (t == 1023) bsum[blockIdx.x] = s[t];
}

__global__ void k_scan2(int* __restrict__ bsum, int* __restrict__ rowptr, int nb){
  if (threadIdx.x == 0 && blockIdx.x == 0){
    int run = 0;
    for (int b = 0; b < nb; b++){ int v = bsum[b]; bsum[b] = run; run += v; }
    rowptr[0] = 0;
  }
}

__global__ __launch_bounds__(1024) void k_scan3(int* __restrict__ rowptr,
                                                const int* __restrict__ bsum){
  int i = blockIdx.x*1024 + threadIdx.x;
  if (i < N_NODESC) rowptr[i+1] += bsum[blockIdx.x];
}

__global__ void k_scatter(const int* __restrict__ ei, const int* __restrict__ rowptr,
                          int* __restrict__ cnt, int* __restrict__ esrc){
  int e = blockIdx.x*256 + threadIdx.x;
  if (e >= E_TOTC) return;
  int src, dst;
  if (e < N_EDGESC){ src = ei[e]; dst = ei[N_EDGESC + e]; }
  else { src = dst = e - N_EDGESC; }
  int pos = rowptr[dst] + atomicAdd(&cnt[dst], 1);
  esrc[pos] = src;
}

// ---------------- layer-1 attention logit precompute ----------------
__global__ void k_wa1(const float* __restrict__ W1, const float* __restrict__ a_src1,
                      const float* __restrict__ a_dst1, float* __restrict__ Wa1){
  int i = blockIdx.x*256 + threadIdx.x;
  if (i >= F_INC*2*HEADS1C) return;
  int d = i / (2*HEADS1C), c = i % (2*HEADS1C);
  const float* a = (c < HEADS1C) ? a_src1 : a_dst1;
  int h = (c < HEADS1C) ? c : c - HEADS1C;
  float s = 0.f;
  for (int j = 0; j < D1C; j++) s += W1[d*F1C + h*D1C + j] * a[h*D1C + j];
  Wa1[d*(2*HEADS1C) + c] = s;
}

// one thread per node; acc[20] in regs; x read once via float2.
__global__ __launch_bounds__(256) void k_att1(const float* __restrict__ x,
                                              const float* __restrict__ Wa1,
                                              float* __restrict__ att1){
  int n = blockIdx.x*256 + threadIdx.x;
  if (n >= N_NODESC) return;
  const float* xr = x + (size_t)n*F_INC;
  float acc[20];
  #pragma unroll
  for (int c = 0; c < 20; c++) acc[c] = 0.f;
  for (int d0 = 0; d0 < F_INC; d0 += 2){
    float2 xv = *(const float2*)(xr + d0);
    const float* w0 = Wa1 + d0*20;
    #pragma unroll
    for (int c = 0; c < 20; c++)
      acc[c] += xv.x*w0[c] + xv.y*w0[20 + c];
  }
  float* o = att1 + (size_t)n*20;
  #pragma unroll
  for (int j = 0; j < 10; j++){
    float2 ov; ov.x = acc[2*j]; ov.y = acc[2*j+1];
    *(float2*)(o + 2*j) = ov;
  }
}

// one thread per node, all 10 heads at once; float2-vectorized gathers.
__global__ __launch_bounds__(256) void k_stats1(const float* __restrict__ att1,
                                                const int* __restrict__ rowptr,
                                                const int* __restrict__ esrc,
                                                float* __restrict__ stat1){
  int n = blockIdx.x*256 + threadIdx.x;
  if (n >= N_NODESC) return;
  float ad[10];
  {
    const float* a = att1 + (size_t)n*20 + 10;
    #pragma unroll
    for (int j = 0; j < 5; j++){
      float2 v = *(const float2*)(a + 2*j);
      ad[2*j] = v.x; ad[2*j+1] = v.y;
    }
  }
  int b = rowptr[n], e = rowptr[n+1];
  float m[10];
  #pragma unroll
  for (int h = 0; h < 10; h++) m[h] = -1e30f;
  for (int p = b; p < e; p += 2){
    int s0 = esrc[p];
    int s1 = esrc[(p+1 < e) ? p+1 : p];
    float2 v0[5], v1[5];
    #pragma unroll
    for (int j = 0; j < 5; j++) v0[j] = *(const float2*)(att1 + (size_t)s0*20 + 2*j);
    #pragma unroll
    for (int j = 0; j < 5; j++) v1[j] = *(const float2*)(att1 + (size_t)s1*20 + 2*j);
    #pragma unroll
    for (int h = 0; h < 10; h++){
      float a0 = (h & 1) ? v0[h>>1].y : v0[h>>1].x;
      m[h] = fmaxf(m[h], lrelu(a0 + ad[h]));
    }
    if (p+1 < e){
      #pragma unroll
      for (int h = 0; h < 10; h++){
        float a1 = (h & 1) ? v1[h>>1].y : v1[h>>1].x;
        m[h] = fmaxf(m[h], lrelu(a1 + ad[h]));
      }
    }
  }
  float den[10];
  #pragma unroll
  for (int h = 0; h < 10; h++) den[h] = 0.f;
  for (int p = b; p < e; p += 2){
    int s0 = esrc[p];
    int s1 = esrc[(p+1 < e) ? p+1 : p];
    float2 v0[5], v1[5];
    #pragma unroll
    for (int j = 0; j < 5; j++) v0[j] = *(const float2*)(att1 + (size_t)s0*20 + 2*j);
    #pragma unroll
    for (int j = 0; j < 5; j++) v1[j] = *(const float2*)(att1 + (size_t)s1*20 + 2*j);
    #pragma unroll
    for (int h = 0; h < 10; h++){
      float a0 = (h & 1) ? v0[h>>1].y : v0[h>>1].x;
      den[h] += expf(lrelu(a0 + ad[h]) - m[h]);
    }
    if (p+1 < e){
      #pragma unroll
      for (int h = 0; h < 10; h++){
        float a1 = (h & 1) ? v1[h>>1].y : v1[h>>1].x;
        den[h] += expf(lrelu(a1 + ad[h]) - m[h]);
      }
    }
  }
  float* o = stat1 + (size_t)n*20;
  #pragma unroll
  for (int h = 0; h < 10; h++){
    o[h] = m[h];
    o[10 + h] = 1.f/(den[h] + 1e-16f);
  }
}

// LDS-free aggregation (v9): lane = feature d; coalesced x gathers, alpha
// broadcast via shfl; 4 independent waves per block, zero LDS/barriers.
__global__ __launch_bounds__(256) void k_agg1(
    const float* __restrict__ x, const float* __restrict__ att1,
    const float* __restrict__ stat1, const int* __restrict__ rowptr,
    const int* __restrict__ esrc, ushort_t* __restrict__ zc, int base){
  int wv = threadIdx.x >> 6;
  int l  = threadIdx.x & 63;
  int nl = blockIdx.x*4 + wv;          // chunk-local node index (grid = R/4)
  int n  = base + nl;
  int b = rowptr[n], e = rowptr[n+1];
  float ad = 0.f, mm = 0.f, rd = 0.f;
  if (l < HEADS1C){
    ad = att1[n*20 + 10 + l];
    mm = stat1[n*20 + l];
    rd = stat1[n*20 + 10 + l];
  }
  float acc0[10], acc1[10];
  #pragma unroll
  for (int h = 0; h < 10; h++){ acc0[h] = 0.f; acc1[h] = 0.f; }
  bool lo14 = (l < 14);
  for (int p = b; p < e; p += 4){
    int c = e - p; if (c > 4) c = 4;
    int ss[4];
    #pragma unroll
    for (int j = 0; j < 4; j++) ss[j] = esrc[p + (j < c ? j : 0)];
    float alv[4];
    #pragma unroll
    for (int j = 0; j < 4; j++){
      float av = (l < HEADS1C) ? att1[ss[j]*20 + l] : 0.f;
      float ev = lrelu(av + ad);
      alv[j] = (j < c) ? expf(ev - mm) * rd : 0.f;
    }
    float xv0[4], xv1[4];
    #pragma unroll
    for (int j = 0; j < 4; j++){
      const float* xr = x + (size_t)ss[j]*F_INC;
      xv0[j] = xr[l];
      xv1[j] = lo14 ? xr[64 + l] : 0.f;
    }
    #pragma unroll
    for (int h = 0; h < 10; h++){
      float a0 = __shfl(alv[0], h);
      float a1 = __shfl(alv[1], h);
      float a2 = __shfl(alv[2], h);
      float a3 = __shfl(alv[3], h);
      float s0 = a0*xv0[0] + a1*xv0[1] + a2*xv0[2] + a3*xv0[3];
      float s1 = a0*xv1[0] + a1*xv1[1] + a2*xv1[2] + a3*xv1[3];
      acc0[h] += s0;
      acc1[h] += s1;
    }
  }
  ushort_t* zr = zc + (size_t)nl*F1C;
  #pragma unroll
  for (int h = 0; h < 10; h++){
    zr[h*78 + l] = f2bf(acc0[h]);
    if (lo14) zr[h*78 + 64 + l] = f2bf(acc1[h]);
  }
}

// ---------------- weight pre-transpose (zero-padded bf16) ----------------
__global__ void k_prepW1(const float* __restrict__ W1, ushort_t* __restrict__ W1t){
  // W1t[h][n(80)][k(96)] = bf16(W1[k][h*78+n]) with zero pad
  int i = blockIdx.x*256 + threadIdx.x;
  if (i >= HEADS1C*80*96) return;
  int h = i / (80*96), rem = i % (80*96), n = rem / 96, k = rem % 96;
  float v = (n < D1C && k < F_INC) ? W1[(size_t)k*F1C + h*D1C + n] : 0.f;
  W1t[i] = f2bf(v);
}

// W2f[h][n(128)][k(96)] = bf16(W2[h*78+k][n]) with zero pad in k (78..95)
__global__ void k_prepW2f(const float* __restrict__ W2, ushort_t* __restrict__ W2f){
  int i = blockIdx.x*256 + threadIdx.x;
  if (i >= HEADS1C*128*96) return;
  int h = i / (128*96), rem = i % (128*96), n = rem / 96, k = rem % 96;
  float v = (k < D1C) ? W2[(size_t)(h*D1C + k)*OUT2C + n] : 0.f;
  W2f[i] = f2bf(v);
}

// generic: Wt[n][k(KB)] = bf16(W[k][n]) zero-padded in k
__global__ void k_prepWt(const float* __restrict__ W, ushort_t* __restrict__ Wt,
                         int Kdim, int Ndim, int KB){
  int i = blockIdx.x*256 + threadIdx.x;
  if (i >= Ndim*KB) return;
  int n = i / KB, k = i % KB;
  float v = (k < Kdim) ? W[(size_t)k*Ndim + n] : 0.f;
  Wt[i] = f2bf(v);
}

__global__ void k_cast_bf(const float* __restrict__ in, ushort_t* __restrict__ o, int n){
  int i = blockIdx.x*256 + threadIdx.x;
  if (i < n) o[i] = f2bf(in[i]);
}

// ---------------- MFMA bf16 GEMM: C[M,N] = act(A @ Bt^T + bias), bf16 out ---
template<int BN, int NT, int KB, int KVAL, int ACT, bool HASBIAS>
__global__ __launch_bounds__(256) void mfma_gemm(
    const ushort_t* __restrict__ A, const ushort_t* __restrict__ Bt,
    const float* __restrict__ bias, ushort_t* __restrict__ C,
    int M, int N, int lda, int ldc,
    int zsA, int zsBt, int zsC, int zsBias)
{
  __shared__ unsigned int As[64][20];   // 64 rows x 32 bf16 (+pad)
  __shared__ unsigned int Bs[BN][20];
  int z = blockIdx.z;
  A += (size_t)z*zsA; Bt += (size_t)z*zsBt; C += (size_t)z*zsC;
  const float* bz = HASBIAS ? (bias + (size_t)z*zsBias) : nullptr;
  int m0 = blockIdx.x*64;
  int n0 = blockIdx.y*BN;
  int t = threadIdx.x;
  int w = t >> 6, lane = t & 63;
  int q = lane >> 4, li = lane & 15;
  f32x4 acc[NT];
  #pragma unroll
  for (int i = 0; i < NT; i++) acc[i] = (f32x4){0.f,0.f,0.f,0.f};

  int am = t >> 2;           // staged row 0..63
  int ak0 = (t & 3)*8;       // short col base 0,8,16,24
  int gm = m0 + am;
  bool rv = (gm < M);

  #pragma unroll
  for (int ki = 0; ki < KB/32; ki++){
    const int kt = ki*32;
    int nv;
    if (ki == KB/32 - 1){
      int d = KVAL - ak0; nv = d < 0 ? 0 : (d > 8 ? 8 : d);
    } else nv = 8;
    {
      unsigned u0=0u, u1=0u, u2=0u, u3=0u;
      if (rv && nv > 0){
        const unsigned int* ap = (const unsigned int*)(A + (size_t)gm*lda + kt + ak0);
        u0 = ap[0]; u1 = ap[1]; u2 = ap[2]; u3 = ap[3];
        int ndw = nv >> 1;
        if (ndw < 4) u3 = 0u;
        if (ndw < 3) u2 = 0u;
        if (ndw < 2) u1 = 0u;
      }
      int c0 = (t & 3)*4;
      As[am][c0] = u0; As[am][c0+1] = u1; As[am][c0+2] = u2; As[am][c0+3] = u3;
    }
    for (int g = t; g < BN*4; g += 256){
      int n = g >> 2, c0 = (g & 3)*4;
      const unsigned int* bp = (const unsigned int*)(Bt + (size_t)(n0 + n)*KB + kt + c0*2);
      Bs[n][c0] = bp[0]; Bs[n][c0+1] = bp[1]; Bs[n][c0+2] = bp[2]; Bs[n][c0+3] = bp[3];
    }
    __syncthreads();
    U4S8 a; a.u = *(const uint4v*)&As[w*16 + li][q*4];
    #pragma unroll
    for (int nt = 0; nt < NT; nt++){
      U4S8 b; b.u = *(const uint4v*)&Bs[nt*16 + li][q*4];
      acc[nt] = __builtin_amdgcn_mfma_f32_16x16x32_bf16(a.s, b.s, acc[nt], 0, 0, 0);
    }
    __syncthreads();
  }
  #pragma unroll
  for (int nt = 0; nt < NT; nt++){
    int col = n0 + nt*16 + li;
    if (col >= N) continue;
    float bv = HASBIAS ? bz[col] : 0.f;
    #pragma unroll
    for (int r = 0; r < 4; r++){
      int gmr = m0 + w*16 + q*4 + r;
      if (gmr >= M) continue;
      float v = acc[nt][r] + bv;
      if (ACT == 1) v = fmaxf(v, 0.f);
      else if (ACT == 2) v = (v > 0.f) ? v : (__expf(v) - 1.0f);
      C[(size_t)gmr*ldc + col] = f2bf(v);
    }
  }
}

// ---------------- FUSED layer-1 GEMM + projection (v11, best measured) -----
// h2pre[m, 0:128] = sum_h  elu( zc[m, h*78:+78] @ W1h + b1_h )  @  W2[h*78:+78, 0:128]
// + fused att2 logits from the bf16-rounded h2pre values.
// Split weight buffers Bs1/Bs2 (flat stride 48), 2 bar_lds/head, T14 reg
// staging, one-head-ahead A prefetch, (256,3) reg cap.
__global__ __launch_bounds__(256, 3) void mfma_fused12(
    const ushort_t* __restrict__ zc, const ushort_t* __restrict__ W1t,
    const float* __restrict__ b1, const ushort_t* __restrict__ W2f,
    ushort_t* __restrict__ h2pre, float* __restrict__ att2,
    const float* __restrict__ a_src2, const float* __restrict__ a_dst2,
    int M)
{
  __shared__ unsigned int Bs1[80*48];   // W1t[h] flat: 80 rows x 48 dw
  __shared__ unsigned int Bs2[128*48];  // W2f[h] flat: 128 rows x 48 dw
  __shared__ unsigned int Ts[64][52];   // T bf16 (96 shorts + pad), wave-private rows
  int m0 = blockIdx.x*64;
  int t = threadIdx.x;
  int w = t >> 6, lane = t & 63;
  int q = lane >> 4, li = lane & 15;

  const uint4v* w1v = (const uint4v*)W1t;   // [h*960 + g] 16B groups
  const uint4v* w2v = (const uint4v*)W2f;   // [h*1536 + g]

  // ---- staging-register helpers (T14 split: issue early, ds_write late) ----
  uint4v rw1[4], rw2[6];
  auto issueW1 = [&](int h){
    #pragma unroll
    for (int g0 = 0; g0 < 4; g0++){
      int g = t + g0*256;
      if (g < 960) rw1[g0] = w1v[(size_t)h*960 + g];
    }
  };
  auto writeW1 = [&](){
    #pragma unroll
    for (int g0 = 0; g0 < 4; g0++){
      int g = t + g0*256;
      if (g < 960) *(uint4v*)&Bs1[g*4] = rw1[g0];
    }
  };
  auto issueW2 = [&](int h){
    #pragma unroll
    for (int g0 = 0; g0 < 6; g0++)
      rw2[g0] = w2v[(size_t)h*1536 + t + g0*256];
  };
  auto writeW2 = [&](){
    #pragma unroll
    for (int g0 = 0; g0 < 6; g0++){
      int g = t + g0*256;
      *(uint4v*)&Bs2[g*4] = rw2[g0];
    }
  };

  f32x4 acc2[8];
  #pragma unroll
  for (int i = 0; i < 8; i++) acc2[i] = (f32x4){0.f,0.f,0.f,0.f};

  issueW1(0);                           // both head-0 weight tiles in flight
  issueW2(0);

  // zero Ts pad dwords 39..47 (cols 78..95) once (read in stage-2 ki=2;
  // published by the prologue barrier)
  for (int i = t; i < 64*9; i += 256) Ts[i/9][39 + i%9] = 0u;

  // this lane's A row: m0 + w*16 + li; k-chunk q (shorts q*8..q*8+7 per 32-k tile)
  int ar = m0 + w*16 + li;
  bool rv = (ar < M);
  const unsigned int* abase = (const unsigned int*)(zc + (size_t)ar*F1C);

  // A-fragment loader for head h: af[ki], k = ki*32 + q*8 (head slice is 78 wide)
  auto lda = [&](int h, uint4v* af){
    af[0] = (uint4v){0u,0u,0u,0u};
    af[1] = (uint4v){0u,0u,0u,0u};
    af[2] = (uint4v){0u,0u,0u,0u};
    if (rv){
      const unsigned int* p = abase + h*39 + q*4;    // h*78 shorts = h*39 dwords
      af[0][0]=p[0];  af[0][1]=p[1];  af[0][2]=p[2];  af[0][3]=p[3];
      af[1][0]=p[16]; af[1][1]=p[17]; af[1][2]=p[18]; af[1][3]=p[19];
      if (q < 2){                                    // k 64..79 only (78,79 zeroed)
        af[2][0]=p[32]; af[2][1]=p[33]; af[2][2]=p[34]; af[2][3]=p[35];
        if (q == 1) af[2][3] = 0u;
      }
    }
  };

  uint4v acur[3], anxt[3];
  lda(0, acur);

  writeW1();                            // Bs1 <- W1[0] (vmcnt wait, once)
  bar_lds();                            // Bs1 + Ts-pad visible

  #pragma unroll 1
  for (int h = 0; h < HEADS1C; h++){
    int hn = (h+1 < HEADS1C) ? h+1 : 0;
    writeW2();                          // Bs2 <- W2[h]; rw2 dies (stage-1 reads Bs1)
    issueW1(hn);                        // W1[h+1] -> regs, in flight over stage-1
    // per-head bias: 5 per lane (cols nt*16+li)
    float bv[5];
    #pragma unroll
    for (int nt = 0; nt < 5; nt++){
      int col = nt*16 + li;
      bv[nt] = (col < D1C) ? b1[h*D1C + col] : 0.f;
    }

    // stage-1 MFMA: T(64x80) = zc_h @ W1h (A from registers, B from Bs1)
    f32x4 acc1[5];
    #pragma unroll
    for (int i = 0; i < 5; i++) acc1[i] = (f32x4){0.f,0.f,0.f,0.f};
    #pragma unroll
    for (int ki = 0; ki < 3; ki++){
      U4S8 a; a.u = acur[ki];
      #pragma unroll
      for (int nt = 0; nt < 5; nt++){
        U4S8 b; b.u = *(const uint4v*)&Bs1[(nt*16 + li)*48 + ki*16 + q*4];
        acc1[nt] = __builtin_amdgcn_mfma_f32_16x16x32_bf16(a.s, b.s, acc1[nt], 0, 0, 0);
      }
    }
    // bias + fast elu -> bf16 into Ts (wave-private rows)
    #pragma unroll
    for (int nt = 0; nt < 5; nt++){
      int col = nt*16 + li;
      #pragma unroll
      for (int r = 0; r < 4; r++){
        int row = w*16 + q*4 + r;
        float v = elu_fast(acc1[nt][r] + bv[nt]);
        ((ushort_t*)&Ts[row][0])[col] = f2bf(v);
      }
    }
    // prefetch next head's A frags (zc, L3) — stays in flight across barriers
    lda(hn, anxt);

    bar_lds();                          // stage-1 Bs1 reads done; Bs2+Ts visible
    writeW1();                          // Bs1 <- W1[h+1]; rw1 dies (stage-2 reads Bs2)
    issueW2(hn);                        // W2[h+1] -> regs, in flight over stage-2

    // stage-2 MFMA: acc2 += T @ W2f[h] (A from own Ts rows, B from Bs2)
    #pragma unroll
    for (int ki = 0; ki < 3; ki++){
      U4S8 a; a.u = *(const uint4v*)&Ts[w*16 + li][ki*16 + q*4];
      #pragma unroll
      for (int nt = 0; nt < 8; nt++){
        U4S8 b; b.u = *(const uint4v*)&Bs2[(nt*16 + li)*48 + ki*16 + q*4];
        acc2[nt] = __builtin_amdgcn_mfma_f32_16x16x32_bf16(a.s, b.s, acc2[nt], 0, 0, 0);
      }
    }
    bar_lds();                          // stage-2 Bs2 reads done; Bs1 writes visible
    acur[0] = anxt[0]; acur[1] = anxt[1]; acur[2] = anxt[2];
  }

  // ---- epilogue: h2pre bf16 + fused att2 logits (from bf16-rounded vals) ---
  float as2[8], ad2[8];
  #pragma unroll
  for (int nt = 0; nt < 8; nt++){
    int col = nt*16 + li;
    as2[nt] = a_src2[col];
    ad2[nt] = a_dst2[col];
  }
  #pragma unroll
  for (int r = 0; r < 4; r++){
    int gmr = m0 + w*16 + q*4 + r;
    float p0 = 0.f, p1 = 0.f;
    ushort_t hv[8];
    #pragma unroll
    for (int nt = 0; nt < 8; nt++){
      ushort_t hb = f2bf(acc2[nt][r]);
      float vb = bf2f(hb);
      p0 += vb*as2[nt]; p1 += vb*ad2[nt];
      hv[nt] = hb;
    }
    #pragma unroll
    for (int off = 1; off < 16; off <<= 1){
      p0 += __shfl_xor(p0, off);
      p1 += __shfl_xor(p1, off);
    }
    if (gmr < M){
      #pragma unroll
      for (int nt = 0; nt < 8; nt++)
        h2pre[(size_t)gmr*OUT2C + nt*16 + li] = hv[nt];
      if (li == 0){
        att2[(size_t)gmr*2]     = p0;
        att2[(size_t)gmr*2 + 1] = p1;
      }
    }
  }
}

// per node: max + 1/(sum exp) + per-edge alpha precompute (3rd pass).
// ealpha[p] = expf(lrelu(att2[esrc[p]]+ad) - m)*rd — the exact expression
// k_agg2 used to recompute redundantly on all 64 lanes per edge.
__global__ void k_stats2(const float* __restrict__ att2, const int* __restrict__ rowptr,
                         const int* __restrict__ esrc, float* __restrict__ stat2,
                         float* __restrict__ ealpha){
  int n = blockIdx.x*256 + threadIdx.x;
  if (n >= N_NODESC) return;
  float ad = att2[n*2+1];
  int b = rowptr[n], e = rowptr[n+1];
  float m = -1e30f;
  for (int p = b; p < e; p += 4){
    int c = e - p; if (c > 4) c = 4;
    float v[4];
    #pragma unroll
    for (int j = 0; j < 4; j++){ int s = esrc[p + (j < c ? j : 0)]; v[j] = att2[s*2]; }
    #pragma unroll
    for (int j = 0; j < 4; j++) if (j < c) m = fmaxf(m, lrelu(v[j] + ad));
  }
  float den = 0.f;
  for (int p = b; p < e; p += 4){
    int c = e - p; if (c > 4) c = 4;
    float v[4];
    #pragma unroll
    for (int j = 0; j < 4; j++){ int s = esrc[p + (j < c ? j : 0)]; v[j] = att2[s*2]; }
    #pragma unroll
    for (int j = 0; j < 4; j++) if (j < c) den += expf(lrelu(v[j] + ad) - m);
  }
  float rd = 1.f/(den + 1e-16f);
  stat2[n*2] = m;
  stat2[n*2+1] = rd;
  for (int p = b; p < e; p++){
    int s = esrc[p];
    ealpha[p] = expf(lrelu(att2[s*2] + ad) - m) * rd;
  }
}

// wave per node; alpha loaded precomputed (wave-uniform -> scalarizable);
// inner loop is pure gather + FMA.  al[j]=0 padding replaces the j<c guard
// (adds exact zeros — sums unchanged).
__global__ void k_agg2(const ushort_t* __restrict__ h2pre,
                       const float* __restrict__ ealpha,
                       const int* __restrict__ rowptr,
                       const int* __restrict__ esrc, const float* __restrict__ b2,
                       const float* __restrict__ w_gate, const float* __restrict__ b_gate,
                       float* __restrict__ h2, float* __restrict__ wnode){
  int n = blockIdx.x*4 + (threadIdx.x >> 6);
  int l = threadIdx.x & 63;
  if (n >= N_NODESC) return;
  int b = rowptr[n], e = rowptr[n+1];
  float a0 = 0.f, a1 = 0.f;
  for (int p = b; p < e; p += 4){
    int c = e - p; if (c > 4) c = 4;
    int ss[4]; float al[4];
    #pragma unroll
    for (int j = 0; j < 4; j++) ss[j] = esrc[p + (j < c ? j : 0)];
    #pragma unroll
    for (int j = 0; j < 4; j++) al[j] = (j < c) ? ealpha[p + j] : 0.f;
    unsigned u[4];
    #pragma unroll
    for (int j = 0; j < 4; j++) u[j] = *(const unsigned*)(h2pre + (size_t)ss[j]*OUT2C + 2*l);
    #pragma unroll
    for (int j = 0; j < 4; j++){
      a0 += al[j] * bf2f((ushort_t)(u[j] & 0xffffu));
      a1 += al[j] * bf2f((ushort_t)(u[j] >> 16));
    }
  }
  float v0 = fmaxf(a0 + b2[2*l],   0.f);
  float v1 = fmaxf(a1 + b2[2*l+1], 0.f);
  float2 hv; hv.x = v0; hv.y = v1;
  *(float2*)(h2 + (size_t)n*OUT2C + 2*l) = hv;
  float pp = v0*w_gate[2*l] + v1*w_gate[2*l+1];
  #pragma unroll
  for (int off = 32; off; off >>= 1) pp += __shfl_xor(pp, off);
  if (l == 0) wnode[n] = 1.f/(1.f + expf(-(pp + b_gate[0])));
}

// one block per graph: weighted-sum + max readout, bf16 out into xcb[:, 0:256]
__global__ __launch_bounds__(128) void k_readout(const float* __restrict__ h2,
                                                 const float* __restrict__ wnode,
                                                 const int* __restrict__ batch,
                                                 ushort_t* __restrict__ xcb){
  __shared__ int lohi[2];
  int g = blockIdx.x, t = threadIdx.x;
  if (t == 0){
    int lo = 0, hi = N_NODESC;
    while (lo < hi){ int mid = (lo+hi) >> 1; if (batch[mid] < g) lo = mid+1; else hi = mid; }
    lohi[0] = lo;
    int lo2 = lo; hi = N_NODESC;
    while (lo2 < hi){ int mid = (lo2+hi) >> 1; if (batch[mid] < g+1) lo2 = mid+1; else hi = mid; }
    lohi[1] = lo2;
  }
  __syncthreads();
  int lo = lohi[0], hi = lohi[1];
  float sum = 0.f, mx = 0.f;
  for (int n = lo; n < hi; n++){
    float v = h2[(size_t)n*OUT2C + t];
    sum += v * wnode[n];
    mx = fmaxf(mx, v);
  }
  xcb[(size_t)g*512 + t] = f2bf(sum);
  xcb[(size_t)g*512 + 128 + t] = f2bf(mx);
}

__global__ void k_final(const ushort_t* __restrict__ f2b, const float* __restrict__ W_out,
                        const float* __restrict__ b_out, float* __restrict__ out){
  int g = blockIdx.x*4 + (threadIdx.x >> 6);
  int l = threadIdx.x & 63;
  if (g >= N_GRAPHSC) return;
  float s = 0.f;
  #pragma unroll
  for (int k = 0; k < 4; k++) s += bf2f(f2b[(size_t)g*256 + l + 64*k]) * W_out[l + 64*k];
  #pragma unroll
  for (int off = 32; off; off >>= 1) s += __shfl_xor(s, off);
  if (l == 0) out[g] = s + b_out[0];
}

extern "C" void kernel_launch(void* const* d_in, const int* in_sizes, int n_in,
                              void* d_out, int out_size, void* d_ws, size_t ws_size,
                              hipStream_t stream) {
  const float* x      = (const float*)d_in[0];
  const int*   ei     = (const int*)d_in[1];
  const int*   batch  = (const int*)d_in[2];
  const float* target = (const float*)d_in[3];
  const float* W1     = (const float*)d_in[4];
  const float* a_src1 = (const float*)d_in[5];
  const float* a_dst1 = (const float*)d_in[6];
  const float* b1     = (const float*)d_in[7];
  const float* W2     = (const float*)d_in[8];
  const float* a_src2 = (const float*)d_in[9];
  const float* a_dst2 = (const float*)d_in[10];
  const float* b2     = (const float*)d_in[11];
  const float* w_gate = (const float*)d_in[12];
  const float* b_gate = (const float*)d_in[13];
  const float* W_xt   = (const float*)d_in[14];
  const float* b_xt   = (const float*)d_in[15];
  const float* W_fc1  = (const float*)d_in[16];
  const float* b_fc1  = (const float*)d_in[17];
  const float* W_fc2  = (const float*)d_in[18];
  const float* b_fc2  = (const float*)d_in[19];
  const float* W_out  = (const float*)d_in[20];
  const float* b_out  = (const float*)d_in[21];
  float* out = (float*)d_out;

  // ---- adaptive chunking (C=1 when workspace allows) ----
  const size_t MB = (size_t)1 << 20;
  int C;
  if      (ws_size >= 245*MB) C = 1;
  else if (ws_size >= 150*MB) C = 2;
  else                        C = 4;
  const int R = N_NODESC / C;          // R and R/4 integral for C in {1,2,4}

  char* p = (char*)d_ws;
  auto carve = [&](size_t bytes) -> char* {
    char* r = p; p += (bytes + 255) & ~(size_t)255; return r;
  };
  int*   deg    = (int*)  carve((size_t)N_NODESC*4);
  int*   rowptr = (int*)  carve((size_t)(N_NODESC+1)*4);
  int*   cnt    = (int*)  carve((size_t)N_NODESC*4);
  int*   esrc   = (int*)  carve((size_t)E_TOTC*4);
  int*   bsum   = (int*)  carve(128*4);
  float* Wa1    = (float*)carve((size_t)F_INC*20*4);
  float* att1   = (float*)carve((size_t)N_NODESC*20*4);
  float* stat1  = (float*)carve((size_t)N_NODESC*20*4);
  float* att2   = (float*)carve((size_t)N_NODESC*2*4);
  float* stat2  = (float*)carve((size_t)N_NODESC*2*4);
  float* ealpha = (float*)carve((size_t)E_TOTC*4);
  float* wnode  = (float*)carve((size_t)N_NODESC*4);
  ushort_t* W1t   = (ushort_t*)carve((size_t)HEADS1C*80*96*2);
  ushort_t* W2f   = (ushort_t*)carve((size_t)HEADS1C*128*96*2);
  ushort_t* Wxtt  = (ushort_t*)carve((size_t)256*1280*2);
  ushort_t* Wfc1t = (ushort_t*)carve((size_t)1024*512*2);
  ushort_t* Wfc2t = (ushort_t*)carve((size_t)256*1024*2);
  ushort_t* tb    = (ushort_t*)carve((size_t)N_GRAPHSC*1280*2);
  ushort_t* h2pre = (ushort_t*)carve((size_t)N_NODESC*OUT2C*2);
  ushort_t* xcb   = (ushort_t*)carve((size_t)N_GRAPHSC*512*2);
  ushort_t* f1b   = (ushort_t*)carve((size_t)N_GRAPHSC*1024*2);
  ushort_t* f2b   = (ushort_t*)carve((size_t)N_GRAPHSC*256*2);
  size_t big_bytes = (size_t)R*F1C*2 + 4096;            // zc (bf16) + overread slack
  size_t h2_bytes  = (size_t)N_NODESC*OUT2C*4;          // h2 (fp32)
  char*  BIG = carve(big_bytes > h2_bytes ? big_bytes : h2_bytes);
  ushort_t* zc  = (ushort_t*)BIG;
  float* h2 = (float*)BIG;   // overlays zc AFTER the fused layer-1/2 pass is done

  hipMemsetAsync(deg, 0, (size_t)N_NODESC*4, stream);
  hipMemsetAsync(cnt, 0, (size_t)N_NODESC*4, stream);

  // CSR by destination (self-loops appended)
  k_deg<<<(E_TOTC+255)/256, 256, 0, stream>>>(ei, deg);
  int nb = (N_NODESC + 1023)/1024;
  k_scan1<<<nb, 1024, 0, stream>>>(deg, rowptr, bsum);
  k_scan2<<<1, 64, 0, stream>>>(bsum, rowptr, nb);
  k_scan3<<<nb, 1024, 0, stream>>>(rowptr, bsum);
  k_scatter<<<(E_TOTC+255)/256, 256, 0, stream>>>(ei, rowptr, cnt, esrc);

  // weight prep (bf16 transposed, zero-padded) + target cast
  k_prepW1<<<(HEADS1C*80*96+255)/256, 256, 0, stream>>>(W1, W1t);
  k_prepW2f<<<(HEADS1C*128*96+255)/256, 256, 0, stream>>>(W2, W2f);
  k_prepWt<<<(256*1280+255)/256, 256, 0, stream>>>(W_xt, Wxtt, 1280, 256, 1280);
  k_prepWt<<<(1024*512+255)/256, 256, 0, stream>>>(W_fc1, Wfc1t, 512, 1024, 512);
  k_prepWt<<<(256*1024+255)/256, 256, 0, stream>>>(W_fc2, Wfc2t, 1024, 256, 1024);
  k_cast_bf<<<((N_GRAPHSC*1280)+255)/256, 256, 0, stream>>>(target, tb, N_GRAPHSC*1280);

  // layer-1 attention logits via folded weights (per-node kernels)
  k_wa1<<<(F_INC*20+255)/256, 256, 0, stream>>>(W1, a_src1, a_dst1, Wa1);
  k_att1<<<(N_NODESC+255)/256, 256, 0, stream>>>(x, Wa1, att1);
  k_stats1<<<(N_NODESC+255)/256, 256, 0, stream>>>(att1, rowptr, esrc, stat1);

  // layer-1 (chunked): agg -> zc; FUSED GEMM+elu+projection+att2 -> h2pre,att2
  for (int c = 0; c < C; c++){
    int base = c*R;
    k_agg1<<<R/4, 256, 0, stream>>>(x, att1, stat1, rowptr, esrc, zc, base);
    mfma_fused12<<<(R+63)/64, 256, 0, stream>>>(
        zc, W1t, b1, W2f, h2pre + (size_t)base*OUT2C, att2 + (size_t)base*2,
        a_src2, a_dst2, R);
  }

  // layer-2 softmax stats (+ per-edge alpha) + aggregation
  k_stats2<<<(N_NODESC+255)/256, 256, 0, stream>>>(att2, rowptr, esrc, stat2, ealpha);
  k_agg2<<<(N_NODESC+3)/4, 256, 0, stream>>>(h2pre, ealpha, rowptr, esrc,
                                             b2, w_gate, b_gate, h2, wnode);

  // readout (bf16) + MLP head via MFMA (K multiples of 32 -> KVAL=32, no masks)
  k_readout<<<N_GRAPHSC, 128, 0, stream>>>(h2, wnode, batch, xcb);
  mfma_gemm<128,8,1280,32,0,true><<<dim3(N_GRAPHSC/64, 256/128, 1), 256, 0, stream>>>(
      tb, Wxtt, b_xt, xcb + 256, N_GRAPHSC, 256, 1280, 512, 0,0,0,0);
  mfma_gemm<128,8,512,32,1,true><<<dim3(N_GRAPHSC/64, 1024/128, 1), 256, 0, stream>>>(
      xcb, Wfc1t, b_fc1, f1b, N_GRAPHSC, 1024, 512, 1024, 0,0,0,0);
  mfma_gemm<128,8,1024,32,1,true><<<dim3(N_GRAPHSC/64, 256/128, 1), 256, 0, stream>>>(
      f1b, Wfc2t, b_fc2, f2b, N_GRAPHSC, 256, 1024, 256, 0,0,0,0);
  k_final<<<(N_GRAPHSC+3)/4, 256, 0, stream>>>(f2b, W_out, b_out, out);
}